// Round 8
// baseline (1499.962 us; speedup 1.0000x reference)
//
#include <hip/hip_runtime.h>

typedef float fv2 __attribute__((ext_vector_type(2)));
typedef float fv4 __attribute__((ext_vector_type(4)));
typedef __bf16 bfv8 __attribute__((ext_vector_type(8)));
typedef unsigned short u16v4 __attribute__((ext_vector_type(4)));
typedef unsigned short u16v8 __attribute__((ext_vector_type(8)));
typedef unsigned int u32v2 __attribute__((ext_vector_type(2)));
typedef unsigned int u32v4 __attribute__((ext_vector_type(4)));

#define B_DIM 4
#define L_DIM 8192
#define D_DIM 1024
#define H_NUM 16
#define NSEG 16
#define SEG_S 512
#define M_TOK (B_DIM * L_DIM)  // 32768 rows, all batches fused

__device__ __forceinline__ unsigned short f2bf(float f) {
  unsigned u = __float_as_uint(f);
  u += 0x7fffu + ((u >> 16) & 1u);  // RNE
  return (unsigned short)(u >> 16);
}
__device__ __forceinline__ float bf2f(unsigned short h) {
  return __uint_as_float((unsigned)h << 16);
}
__device__ __forceinline__ unsigned packbf2(float v) {
  unsigned short hb = f2bf(v);
  unsigned short lb = f2bf(v - bf2f(hb));
  return (unsigned)hb | ((unsigned)lb << 16);
}
__device__ __forceinline__ float up_hi(unsigned u) { return __uint_as_float(u << 16); }
__device__ __forceinline__ float up_lo(unsigned u) { return __uint_as_float(u & 0xffff0000u); }

// unpack 8 packed elements (2 x u32v4) -> u16v8 of 8 hi-bf16 and 8 lo-bf16
__device__ __forceinline__ void unpack8(u32v4 a, u32v4 b, u16v8& hi8, u16v8& lo8) {
  u32v4 hi, lo;
  hi[0] = __builtin_amdgcn_perm(a[1], a[0], 0x05040100u);
  hi[1] = __builtin_amdgcn_perm(a[3], a[2], 0x05040100u);
  hi[2] = __builtin_amdgcn_perm(b[1], b[0], 0x05040100u);
  hi[3] = __builtin_amdgcn_perm(b[3], b[2], 0x05040100u);
  lo[0] = __builtin_amdgcn_perm(a[1], a[0], 0x07060302u);
  lo[1] = __builtin_amdgcn_perm(a[3], a[2], 0x07060302u);
  lo[2] = __builtin_amdgcn_perm(b[1], b[0], 0x07060302u);
  lo[3] = __builtin_amdgcn_perm(b[3], b[2], 0x07060302u);
  hi8 = __builtin_bit_cast(u16v8, hi);
  lo8 = __builtin_bit_cast(u16v8, lo);
}
// split 8 fp32 (as raw u32x8) -> hi/lo bf16 planes (identical results to packbf2+unpack8)
__device__ __forceinline__ void split8(const unsigned* pr, u16v8& hi8, u16v8& lo8) {
#pragma unroll
  for (int j = 0; j < 8; ++j) {
    const float v = __uint_as_float(pr[j]);
    const unsigned short hb = f2bf(v);
    hi8[j] = hb;
    lo8[j] = f2bf(v - bf2f(hb));
  }
}

// ---------------- fp32 -> packed (hi|lo<<16) split (weights only) ----------------
__global__ __launch_bounds__(256) void split_pack(
    const float* __restrict__ in, unsigned* __restrict__ outp, int n4) {
  int i = blockIdx.x * 256 + threadIdx.x;
  const int stride = gridDim.x * 256;
  for (; i < n4; i += stride) {
    fv4 v = reinterpret_cast<const fv4*>(in)[i];
    u32v4 p;
#pragma unroll
    for (int j = 0; j < 4; ++j) p[j] = packbf2(v[j]);
    reinterpret_cast<u32v4*>(outp)[i] = p;
  }
}

// ---------------- C[M,N] = A @ B^T, split-bf16 3-product MFMA ----------------
// ASPLIT=1: A is fp32 (split fused into staging). ASPLIT=0: A is packed u32.
// B always packed. Output: Cp packed u32, or fp32 C (+bias).
#define GT_PAD 40
template <int ASPLIT>
__global__ __launch_bounds__(256, 3) void gemm_bt(
    const unsigned* __restrict__ Ap, const unsigned* __restrict__ Bp,
    float* __restrict__ C, const float* __restrict__ bias,
    unsigned* __restrict__ Cp, int M, int N, int K) {
  __shared__ __bf16 sAh[128 * GT_PAD], sAl[128 * GT_PAD];
  __shared__ __bf16 sBh[128 * GT_PAD], sBl[128 * GT_PAD];
  const int tid = threadIdx.x;
  const int lane = tid & 63;
  const int wid = tid >> 6;
  const int wr = wid >> 1, wc = wid & 1;
  const int mBase = blockIdx.y * 128;
  const int nBase = blockIdx.x * 128;

  fv4 acc[4][4] = {};

  const int arowRd = wr * 64 + (lane & 15);
  const int browRd = wc * 64 + (lane & 15);
  const int koff = (lane >> 4) << 3;

  const int srow0 = tid >> 2, srow1 = (256 + tid) >> 2, sch = tid & 3;
  const int ldo0 = srow0 * GT_PAD + sch * 8;
  const int ldo1 = srow1 * GT_PAD + sch * 8;

  u32v4 pa0[2], pa1[2], pb0[2], pb1[2];
  auto LOADK = [&](int k0) {
    const long ga0 = (long)(mBase + srow0) * K + k0 + sch * 8;
    const long ga1 = (long)(mBase + srow1) * K + k0 + sch * 8;
    const long gb0 = (long)(nBase + srow0) * K + k0 + sch * 8;
    const long gb1 = (long)(nBase + srow1) * K + k0 + sch * 8;
    pa0[0] = *(const u32v4*)&Ap[ga0]; pa0[1] = *(const u32v4*)&Ap[ga0 + 4];
    pa1[0] = *(const u32v4*)&Ap[ga1]; pa1[1] = *(const u32v4*)&Ap[ga1 + 4];
    pb0[0] = *(const u32v4*)&Bp[gb0]; pb0[1] = *(const u32v4*)&Bp[gb0 + 4];
    pb1[0] = *(const u32v4*)&Bp[gb1]; pb1[1] = *(const u32v4*)&Bp[gb1 + 4];
  };
  LOADK(0);

  for (int k0 = 0; k0 < K; k0 += 32) {
    __syncthreads();
    {
      u16v8 hi8, lo8;
      if (ASPLIT) split8((const unsigned*)pa0, hi8, lo8);
      else unpack8(pa0[0], pa0[1], hi8, lo8);
      *(u16v8*)&sAh[ldo0] = hi8; *(u16v8*)&sAl[ldo0] = lo8;
      if (ASPLIT) split8((const unsigned*)pa1, hi8, lo8);
      else unpack8(pa1[0], pa1[1], hi8, lo8);
      *(u16v8*)&sAh[ldo1] = hi8; *(u16v8*)&sAl[ldo1] = lo8;
      unpack8(pb0[0], pb0[1], hi8, lo8);
      *(u16v8*)&sBh[ldo0] = hi8; *(u16v8*)&sBl[ldo0] = lo8;
      unpack8(pb1[0], pb1[1], hi8, lo8);
      *(u16v8*)&sBh[ldo1] = hi8; *(u16v8*)&sBl[ldo1] = lo8;
    }
    if (k0 + 32 < K) LOADK(k0 + 32);  // T14: latency hides under barrier+MFMA
    __syncthreads();
    bfv8 fah[4], fal[4], fbh[4], fbl[4];
#pragma unroll
    for (int i = 0; i < 4; ++i) {
      fah[i] = *(const bfv8*)&sAh[(arowRd + i * 16) * GT_PAD + koff];
      fal[i] = *(const bfv8*)&sAl[(arowRd + i * 16) * GT_PAD + koff];
      fbh[i] = *(const bfv8*)&sBh[(browRd + i * 16) * GT_PAD + koff];
      fbl[i] = *(const bfv8*)&sBl[(browRd + i * 16) * GT_PAD + koff];
    }
#pragma unroll
    for (int i = 0; i < 4; ++i)
#pragma unroll
      for (int j = 0; j < 4; ++j) {
        acc[i][j] = __builtin_amdgcn_mfma_f32_16x16x32_bf16(fah[i], fbh[j], acc[i][j], 0, 0, 0);
        acc[i][j] = __builtin_amdgcn_mfma_f32_16x16x32_bf16(fah[i], fbl[j], acc[i][j], 0, 0, 0);
        acc[i][j] = __builtin_amdgcn_mfma_f32_16x16x32_bf16(fal[i], fbh[j], acc[i][j], 0, 0, 0);
      }
  }

  // C/D layout (verified m89): col = lane&15, row = 4*(lane>>4) + reg
  const int crow0 = mBase + wr * 64 + ((lane >> 4) << 2);
  const int ccol0 = nBase + wc * 64 + (lane & 15);
  if (Cp) {
#pragma unroll
    for (int j = 0; j < 4; ++j) {
      const int col = ccol0 + j * 16;
#pragma unroll
      for (int i = 0; i < 4; ++i) {
        const long rb = (long)(crow0 + i * 16) * N + col;
#pragma unroll
        for (int r = 0; r < 4; ++r)
          Cp[rb + (long)r * N] = packbf2(acc[i][j][r]);
      }
    }
  } else {
#pragma unroll
    for (int j = 0; j < 4; ++j) {
      const int col = ccol0 + j * 16;
      const float bv = bias ? bias[col] : 0.f;
#pragma unroll
      for (int i = 0; i < 4; ++i) {
        const long rb = (long)(crow0 + i * 16) * N + col;
#pragma unroll
        for (int r = 0; r < 4; ++r)
          C[rb + (long)r * N] = acc[i][j][r] + bv;
      }
    }
  }
}

// ---------------- per-(b,seg,h) outer products, MFMA-ized, swizzled LDS ----------------
__global__ __launch_bounds__(256) void seg_outer_mfma(
    const unsigned* __restrict__ Kp, const unsigned* __restrict__ Vp,
    float* __restrict__ U, float* __restrict__ Zs) {
  __shared__ __bf16 sAh[64 * 64], sAl[64 * 64];  // akT [d][s]
  __shared__ __bf16 sVh[64 * 64], sVl[64 * 64];  // vT  [e][s]
  __shared__ float sZf[64];
  const int bid = blockIdx.x;            // b*256 + seg*16 + h
  const int b = bid >> 8, seg = (bid >> 4) & 15, h = bid & 15;
  const int tid = threadIdx.x;
  const int lane = tid & 63, w = tid >> 6;
  const int g = lane >> 4, ln16 = lane & 15;
  const long base = ((long)b * L_DIM + (long)seg * SEG_S) * D_DIM + h * 64;

  if (tid < 64) sZf[tid] = 0.f;
  fv4 acc[4] = {};
  float zacc = 0.f;
  const int strow = tid & 63;
  const int sg0 = (tid >> 6) * 16;
  const int wsw = (strow & 7) << 3;
  const int rsw = (ln16 & 7) << 3;

  for (int c = 0; c < 8; ++c) {
    __syncthreads();
#pragma unroll
    for (int jj = 0; jj < 2; ++jj) {
      u16v8 ah, al, vh, vl;
#pragma unroll
      for (int i = 0; i < 8; ++i) {
        const long gidx = base + (long)(c * 64 + sg0 + jj * 8 + i) * D_DIM + strow;
        const unsigned ku = Kp[gidx];
        const unsigned vu = Vp[gidx];
        const float kv = up_hi(ku) + up_lo(ku);
        const float a = kv > 0.f ? kv + 1.f : __expf(kv);
        zacc += a;
        const unsigned short hb = f2bf(a);
        ah[i] = hb;
        al[i] = f2bf(a - bf2f(hb));
        vh[i] = (unsigned short)(vu & 0xffffu);
        vl[i] = (unsigned short)(vu >> 16);
      }
      const int col = (sg0 + jj * 8) ^ wsw;
      *(u16v8*)&sAh[strow * 64 + col] = ah;
      *(u16v8*)&sAl[strow * 64 + col] = al;
      *(u16v8*)&sVh[strow * 64 + col] = vh;
      *(u16v8*)&sVl[strow * 64 + col] = vl;
    }
    __syncthreads();
#pragma unroll
    for (int kf = 0; kf < 2; ++kf) {
      const int so = (kf * 32 + g * 8) ^ rsw;
      bfv8 aH = *(const bfv8*)&sAh[(w * 16 + ln16) * 64 + so];
      bfv8 aL = *(const bfv8*)&sAl[(w * 16 + ln16) * 64 + so];
#pragma unroll
      for (int et = 0; et < 4; ++et) {
        bfv8 bH = *(const bfv8*)&sVh[(et * 16 + ln16) * 64 + so];
        bfv8 bL = *(const bfv8*)&sVl[(et * 16 + ln16) * 64 + so];
        acc[et] = __builtin_amdgcn_mfma_f32_16x16x32_bf16(aH, bH, acc[et], 0, 0, 0);
        acc[et] = __builtin_amdgcn_mfma_f32_16x16x32_bf16(aH, bL, acc[et], 0, 0, 0);
        acc[et] = __builtin_amdgcn_mfma_f32_16x16x32_bf16(aL, bH, acc[et], 0, 0, 0);
      }
    }
  }
  atomicAdd(&sZf[strow], zacc);
  __syncthreads();

  const long ub = (long)bid * 4096;
#pragma unroll
  for (int et = 0; et < 4; ++et)
#pragma unroll
    for (int r = 0; r < 4; ++r)
      U[ub + (long)(w * 16 + g * 4 + r) * 64 + et * 16 + ln16] = acc[et][r];
  if (tid < 64) Zs[(long)bid * 64 + tid] = sZf[tid];
}

// ---------------- exclusive prefix over segments (per b,h) ----------------
__global__ __launch_bounds__(256) void seg_prefix(
    const float* __restrict__ U, const float* __restrict__ Zs,
    float* __restrict__ Mem, float* __restrict__ Zp) {
  const int bh = blockIdx.x;  // b*16 + h
  const int b = bh >> 4, h = bh & 15;
  const int jc = blockIdx.y;  // 0..7
  const int tid = threadIdx.x;
  for (int j = jc * 512 + tid; j < jc * 512 + 512; j += 256) {
    float run = 0.f;
#pragma unroll
    for (int t = 0; t < NSEG; ++t) {
      const long idx = ((long)(b * 256 + t * 16 + h)) * 4096 + j;
      Mem[idx] = run;
      run += U[idx];
    }
  }
  if (jc == 0 && tid < 64) {
    float run = 0.f;
#pragma unroll
    for (int t = 0; t < NSEG; ++t) {
      const long idx = ((long)(b * 256 + t * 16 + h)) * 64 + tid;
      Zp[idx] = run;
      run += Zs[idx];
    }
  }
}

// ---------------- MFMA segment attention: full batch, in-place att over Q ----------------
// NOTE: Qp and Op may alias (in-place): Q is register-loaded before any store.
__global__ __launch_bounds__(512, 6) void attn_seg_mfma(
    const unsigned* Qp, const unsigned* __restrict__ Kp,
    const unsigned* __restrict__ Vp, const int* __restrict__ mask,
    const float* __restrict__ Mem, const float* __restrict__ Zp,
    const float* __restrict__ betas, unsigned* Op) {
  __shared__ __bf16 sKh[64 * 72], sKl[64 * 72];  // K chunk [key][d]; later Mem^T [e][d]
  __shared__ __bf16 sVTh[64 * 64];               // V^T [e][key], swizzled, hi only
  __shared__ __bf16 sP[8][16 * 72];              // per-wave P (bf16) [q][key]
  __shared__ float sMadd[64], sZ[64], sGate[64];

  // T1: bijective XCD swizzle (nwg = 4096): the 4 qblks of one (b,seg,h) share an XCD.
  const int bx = (blockIdx.x & 7) * 512 + (blockIdx.x >> 3);
  const int qblk = bx & 3, h = (bx >> 2) & 15, seg = (bx >> 6) & 15, b = bx >> 10;
  const int shb = b * 256 + seg * 16 + h;
  const int tid = threadIdx.x;
  const int lane = tid & 63, w = tid >> 6;
  const int g = lane >> 4, ln16 = lane & 15;
  const int rsw = (ln16 & 7) << 3;

  // ---- Q fragments (16 queries per wave), packed loads ----
  const int qglob = b * L_DIM + seg * SEG_S + qblk * 128 + w * 16 + ln16;
  const long qbase = (long)qglob * D_DIM + h * 64;
  bfv8 qh[2], ql[2];
#pragma unroll
  for (int dt = 0; dt < 2; ++dt) {
    u32v4 a = *(const u32v4*)&Qp[qbase + dt * 32 + g * 8];
    u32v4 bb = *(const u32v4*)&Qp[qbase + dt * 32 + g * 8 + 4];
    u16v8 hi8, lo8;
    unpack8(a, bb, hi8, lo8);
    qh[dt] = __builtin_bit_cast(bfv8, hi8);
    ql[dt] = __builtin_bit_cast(bfv8, lo8);
  }

  fv4 O[4] = {};
  float m_run = -1e30f, l_run = 0.f;
  const long kvbase0 = ((long)b * L_DIM + (long)seg * SEG_S) * D_DIM + h * 64;

  for (int c = 0; c < 8; ++c) {
    __syncthreads();
    // ---- stage K [64 key][64 d]: 512 thr, 8 els each ----
    {
      const int row = tid >> 3, d0 = (tid & 7) * 8;
      const long ga = kvbase0 + (long)(c * 64 + row) * D_DIM + d0;
      u32v4 a = *(const u32v4*)&Kp[ga], bb = *(const u32v4*)&Kp[ga + 4];
      u16v8 hi8, lo8;
      unpack8(a, bb, hi8, lo8);
      *(u16v8*)&sKh[row * 72 + d0] = hi8;
      *(u16v8*)&sKl[row * 72 + d0] = lo8;
    }
    // ---- stage V^T [64 e][64 key], row-per-thread, XOR-swizzled, hi only ----
    {
      const int e = tid & 63, kg = (tid >> 6) * 8;
      u16v8 hv;
#pragma unroll
      for (int j = 0; j < 8; ++j) {
        const unsigned u = Vp[kvbase0 + (long)(c * 64 + kg + j) * D_DIM + e];
        hv[j] = (unsigned short)(u & 0xffffu);
      }
      *(u16v8*)&sVTh[e * 64 + (kg ^ ((e & 7) << 3))] = hv;
    }
    if (tid < 64)
      sMadd[tid] = (mask[b * L_DIM + seg * SEG_S + c * 64 + tid] == 0) ? -1e9f : 0.f;
    __syncthreads();

    fv4 madd[4];
#pragma unroll
    for (int kt = 0; kt < 4; ++kt) madd[kt] = *(const fv4*)&sMadd[kt * 16 + g * 4];

    // ---- S^T = K . Q^T (split 3-product) ----
    fv4 sc[4];
#pragma unroll
    for (int kt = 0; kt < 4; ++kt) {
      const int ro = (kt * 16 + ln16) * 72 + g * 8;
      bfv8 kh0 = *(const bfv8*)&sKh[ro], kh1 = *(const bfv8*)&sKh[ro + 32];
      bfv8 kl0 = *(const bfv8*)&sKl[ro], kl1 = *(const bfv8*)&sKl[ro + 32];
      fv4 s = {};
      s = __builtin_amdgcn_mfma_f32_16x16x32_bf16(kh0, qh[0], s, 0, 0, 0);
      s = __builtin_amdgcn_mfma_f32_16x16x32_bf16(kh1, qh[1], s, 0, 0, 0);
      s = __builtin_amdgcn_mfma_f32_16x16x32_bf16(kh0, ql[0], s, 0, 0, 0);
      s = __builtin_amdgcn_mfma_f32_16x16x32_bf16(kh1, ql[1], s, 0, 0, 0);
      s = __builtin_amdgcn_mfma_f32_16x16x32_bf16(kl0, qh[0], s, 0, 0, 0);
      s = __builtin_amdgcn_mfma_f32_16x16x32_bf16(kl1, qh[1], s, 0, 0, 0);
      sc[kt] = s;
    }
    // ---- online softmax (defer-max THR=8) ----
    float pmax = -3.0e38f;
#pragma unroll
    for (int kt = 0; kt < 4; ++kt)
#pragma unroll
      for (int r = 0; r < 4; ++r) {
        const float v = __builtin_fmaf(sc[kt][r], 0.125f, madd[kt][r]);
        sc[kt][r] = v;
        pmax = fmaxf(pmax, v);
      }
    pmax = fmaxf(pmax, __shfl_xor(pmax, 16));
    pmax = fmaxf(pmax, __shfl_xor(pmax, 32));
    if (pmax > m_run + 8.f) {
      const float resc = __expf(m_run - pmax);
      l_run *= resc;
#pragma unroll
      for (int et = 0; et < 4; ++et)
#pragma unroll
        for (int r = 0; r < 4; ++r) O[et][r] *= resc;
      m_run = pmax;
    }
    float psum = 0.f;
#pragma unroll
    for (int kt = 0; kt < 4; ++kt) {
      u16v4 pv;
#pragma unroll
      for (int r = 0; r < 4; ++r) {
        const unsigned short hb = f2bf(__expf(sc[kt][r] - m_run));
        pv[r] = hb;
        psum += bf2f(hb);
      }
      *(u16v4*)&sP[w][ln16 * 72 + kt * 16 + g * 4] = pv;
    }
    psum += __shfl_xor(psum, 16);
    psum += __shfl_xor(psum, 32);
    l_run += psum;

    bfv8 pf0 = *(const bfv8*)&sP[w][ln16 * 72 + g * 8];
    bfv8 pf1 = *(const bfv8*)&sP[w][ln16 * 72 + 32 + g * 8];
    // ---- O^T += V^T . P (V hi only, swizzled reads) ----
#pragma unroll
    for (int et = 0; et < 4; ++et) {
      const int rb = (et * 16 + ln16) * 64;
      bfv8 vh0 = *(const bfv8*)&sVTh[rb + ((g * 8) ^ rsw)];
      bfv8 vh1 = *(const bfv8*)&sVTh[rb + ((g * 8 + 32) ^ rsw)];
      fv4 o = O[et];
      o = __builtin_amdgcn_mfma_f32_16x16x32_bf16(vh0, pf0, o, 0, 0, 0);
      o = __builtin_amdgcn_mfma_f32_16x16x32_bf16(vh1, pf1, o, 0, 0, 0);
      O[et] = o;
    }
  }

  // ---- memory-read term ----
  __syncthreads();
  {  // stage Mem^T [e][d] into sKh/sKl (fp32 source, once per block)
    const int e2 = (tid & 31) * 2, d4 = (tid >> 5) * 4;
    const float* Memp = Mem + (long)shb * 4096;
    fv2 ld[4];
#pragma unroll
    for (int i = 0; i < 4; ++i) ld[i] = *(const fv2*)&Memp[(d4 + i) * 64 + e2];
#pragma unroll
    for (int je = 0; je < 2; ++je) {
      u16v4 hv, lv;
#pragma unroll
      for (int i = 0; i < 4; ++i) {
        const unsigned short hb = f2bf(ld[i][je]);
        hv[i] = hb;
        lv[i] = f2bf(ld[i][je] - bf2f(hb));
      }
      *(u16v4*)&sKh[(e2 + je) * 72 + d4] = hv;
      *(u16v4*)&sKl[(e2 + je) * 72 + d4] = lv;
    }
  }
  if (tid < 64) {
    sZ[tid] = Zp[(long)shb * 64 + tid];
    sGate[tid] = 1.f / (1.f + __expf(-betas[h * 64 + tid]));
  }
  __syncthreads();

  // aq = elu(q)+1 in-register; denom = aq . z
  float dpart = 0.f;
#pragma unroll
  for (int dt = 0; dt < 2; ++dt) {
    u16v8 ah, al;
#pragma unroll
    for (int j = 0; j < 8; ++j) {
      const float x = (float)qh[dt][j] + (float)ql[dt][j];
      const float a = x > 0.f ? x + 1.f : __expf(x);
      dpart += a * sZ[dt * 32 + g * 8 + j];
      const unsigned short hb = f2bf(a);
      ah[j] = hb;
      al[j] = f2bf(a - bf2f(hb));
    }
    qh[dt] = __builtin_bit_cast(bfv8, ah);
    ql[dt] = __builtin_bit_cast(bfv8, al);
  }
  dpart += __shfl_xor(dpart, 16);
  dpart += __shfl_xor(dpart, 32);
  const float invden = 1.f / (dpart + 1e-9f);
  const float invl = 1.f / l_run;

  const long obase = (long)qglob * D_DIM + h * 64;
#pragma unroll
  for (int et = 0; et < 4; ++et) {
    const int ro = (et * 16 + ln16) * 72 + g * 8;
    bfv8 mh0 = *(const bfv8*)&sKh[ro], mh1 = *(const bfv8*)&sKh[ro + 32];
    bfv8 ml0 = *(const bfv8*)&sKl[ro], ml1 = *(const bfv8*)&sKl[ro + 32];
    fv4 o = {};
    o = __builtin_amdgcn_mfma_f32_16x16x32_bf16(mh0, qh[0], o, 0, 0, 0);
    o = __builtin_amdgcn_mfma_f32_16x16x32_bf16(mh1, qh[1], o, 0, 0, 0);
    o = __builtin_amdgcn_mfma_f32_16x16x32_bf16(mh0, ql[0], o, 0, 0, 0);
    o = __builtin_amdgcn_mfma_f32_16x16x32_bf16(mh1, ql[1], o, 0, 0, 0);
    o = __builtin_amdgcn_mfma_f32_16x16x32_bf16(ml0, qh[0], o, 0, 0, 0);
    o = __builtin_amdgcn_mfma_f32_16x16x32_bf16(ml1, qh[1], o, 0, 0, 0);
    const fv4 gt = *(const fv4*)&sGate[et * 16 + g * 4];
    u32v4 st;
#pragma unroll
    for (int r = 0; r < 4; ++r) {
      const float att = gt[r] * o[r] * invden + (1.f - gt[r]) * O[et][r] * invl;
      st[r] = packbf2(att);
    }
    *(u32v4*)&Op[obase + et * 16 + g * 4] = st;
  }
}

// ---------------- host launch: fully batch-fused ----------------
extern "C" void kernel_launch(void* const* d_in, const int* in_sizes, int n_in,
                              void* d_out, int out_size, void* d_ws, size_t ws_size,
                              hipStream_t stream) {
  (void)in_sizes; (void)n_in; (void)out_size;
  const float* x     = (const float*)d_in[0];
  const int*   mask  = (const int*)d_in[1];
  const float* wq    = (const float*)d_in[2];
  const float* wk    = (const float*)d_in[3];
  const float* wv    = (const float*)d_in[4];
  const float* wo    = (const float*)d_in[5];
  const float* wob   = (const float*)d_in[6];
  const float* betas = (const float*)d_in[7];
  float* out = (float*)d_out;

  const size_t TOK = (size_t)M_TOK * D_DIM;  // 33.5M elements
  char* ws = (char*)d_ws;
  size_t off = 0;
  auto alloc = [&](size_t bytes) {
    char* p = ws + off;
    off += (bytes + 255) & ~(size_t)255;
    return p;
  };
  unsigned* wsp[4];
  for (int i = 0; i < 4; ++i)
    wsp[i] = (unsigned*)alloc((size_t)D_DIM * D_DIM * 4);  // 4 MiB each
  unsigned* qp = (unsigned*)alloc(TOK * 4);  // 128 MiB
  unsigned* kp = (unsigned*)alloc(TOK * 4);
  unsigned* vp = (unsigned*)alloc(TOK * 4);
  float* U   = (float*)alloc((size_t)B_DIM * NSEG * H_NUM * 4096 * 4);  // 16.8 MiB
  float* Mem = (float*)alloc((size_t)B_DIM * NSEG * H_NUM * 4096 * 4);
  float* Zs  = (float*)alloc((size_t)B_DIM * NSEG * H_NUM * 64 * 4);
  float* Zp  = (float*)alloc((size_t)B_DIM * NSEG * H_NUM * 64 * 4);
  // total ≈ 434 MiB < 512 MiB ws. att output is written IN-PLACE over qp.

  if (off > ws_size) return;

  const float* wsrc[4] = {wq, wk, wv, wo};
  for (int i = 0; i < 4; ++i)
    split_pack<<<512, 256, 0, stream>>>(wsrc[i], wsp[i], D_DIM * D_DIM / 4);

  dim3 ggrid(D_DIM / 128, M_TOK / 128);  // 8 x 256 = 2048 blocks
  gemm_bt<1><<<ggrid, 256, 0, stream>>>((const unsigned*)x, wsp[0], nullptr, nullptr,
                                        qp, M_TOK, D_DIM, D_DIM);
  gemm_bt<1><<<ggrid, 256, 0, stream>>>((const unsigned*)x, wsp[1], nullptr, nullptr,
                                        kp, M_TOK, D_DIM, D_DIM);
  gemm_bt<1><<<ggrid, 256, 0, stream>>>((const unsigned*)x, wsp[2], nullptr, nullptr,
                                        vp, M_TOK, D_DIM, D_DIM);

  seg_outer_mfma<<<B_DIM * NSEG * H_NUM, 256, 0, stream>>>(kp, vp, U, Zs);
  seg_prefix<<<dim3(B_DIM * H_NUM, 8), 256, 0, stream>>>(U, Zs, Mem, Zp);

  attn_seg_mfma<<<B_DIM * NSEG * H_NUM * 4, 512, 0, stream>>>(qp, kp, vp, mask, Mem,
                                                              Zp, betas, qp);

  gemm_bt<0><<<ggrid, 256, 0, stream>>>(qp, wsp[3], out, wob, nullptr,
                                        M_TOK, D_DIM, D_DIM);
}

// Round 9
// 1267.019 us; speedup vs baseline: 1.1839x; 1.1839x over previous
//
#include <hip/hip_runtime.h>

typedef float fv2 __attribute__((ext_vector_type(2)));
typedef float fv4 __attribute__((ext_vector_type(4)));
typedef __bf16 bfv8 __attribute__((ext_vector_type(8)));
typedef unsigned short u16v4 __attribute__((ext_vector_type(4)));
typedef unsigned short u16v8 __attribute__((ext_vector_type(8)));
typedef unsigned int u32v2 __attribute__((ext_vector_type(2)));
typedef unsigned int u32v4 __attribute__((ext_vector_type(4)));

#define B_DIM 4
#define L_DIM 8192
#define D_DIM 1024
#define H_NUM 16
#define NSEG 16
#define SEG_S 512
#define M_TOK (B_DIM * L_DIM)  // 32768 rows, all batches fused

__device__ __forceinline__ unsigned short f2bf(float f) {
  unsigned u = __float_as_uint(f);
  u += 0x7fffu + ((u >> 16) & 1u);  // RNE
  return (unsigned short)(u >> 16);
}
__device__ __forceinline__ float bf2f(unsigned short h) {
  return __uint_as_float((unsigned)h << 16);
}
__device__ __forceinline__ unsigned packbf2(float v) {
  unsigned short hb = f2bf(v);
  unsigned short lb = f2bf(v - bf2f(hb));
  return (unsigned)hb | ((unsigned)lb << 16);
}
__device__ __forceinline__ float up_hi(unsigned u) { return __uint_as_float(u << 16); }
__device__ __forceinline__ float up_lo(unsigned u) { return __uint_as_float(u & 0xffff0000u); }

// unpack 8 packed elements (2 x u32v4) -> u16v8 of 8 hi-bf16 and 8 lo-bf16
__device__ __forceinline__ void unpack8(u32v4 a, u32v4 b, u16v8& hi8, u16v8& lo8) {
  u32v4 hi, lo;
  hi[0] = __builtin_amdgcn_perm(a[1], a[0], 0x05040100u);
  hi[1] = __builtin_amdgcn_perm(a[3], a[2], 0x05040100u);
  hi[2] = __builtin_amdgcn_perm(b[1], b[0], 0x05040100u);
  hi[3] = __builtin_amdgcn_perm(b[3], b[2], 0x05040100u);
  lo[0] = __builtin_amdgcn_perm(a[1], a[0], 0x07060302u);
  lo[1] = __builtin_amdgcn_perm(a[3], a[2], 0x07060302u);
  lo[2] = __builtin_amdgcn_perm(b[1], b[0], 0x07060302u);
  lo[3] = __builtin_amdgcn_perm(b[3], b[2], 0x07060302u);
  hi8 = __builtin_bit_cast(u16v8, hi);
  lo8 = __builtin_bit_cast(u16v8, lo);
}
// split 8 fp32 (as raw u32x8) -> hi/lo bf16 planes (identical results to packbf2+unpack8)
__device__ __forceinline__ void split8(const unsigned* pr, u16v8& hi8, u16v8& lo8) {
#pragma unroll
  for (int j = 0; j < 8; ++j) {
    const float v = __uint_as_float(pr[j]);
    const unsigned short hb = f2bf(v);
    hi8[j] = hb;
    lo8[j] = f2bf(v - bf2f(hb));
  }
}

// ---------------- fp32 -> packed (hi|lo<<16) split (weights only) ----------------
__global__ __launch_bounds__(256) void split_pack(
    const float* __restrict__ in, unsigned* __restrict__ outp, int n4) {
  int i = blockIdx.x * 256 + threadIdx.x;
  const int stride = gridDim.x * 256;
  for (; i < n4; i += stride) {
    fv4 v = reinterpret_cast<const fv4*>(in)[i];
    u32v4 p;
#pragma unroll
    for (int j = 0; j < 4; ++j) p[j] = packbf2(v[j]);
    reinterpret_cast<u32v4*>(outp)[i] = p;
  }
}

// ---------------- C[M,N] = A @ B^T, split-bf16 3-product MFMA ----------------
// ASPLIT=1: A is fp32 (split fused into staging). ASPLIT=0: A is packed u32.
#define GT_PAD 40
template <int ASPLIT>
__global__ __launch_bounds__(256, 3) void gemm_bt(
    const unsigned* __restrict__ Ap, const unsigned* __restrict__ Bp,
    float* __restrict__ C, const float* __restrict__ bias,
    unsigned* __restrict__ Cp, int M, int N, int K) {
  __shared__ __bf16 sAh[128 * GT_PAD], sAl[128 * GT_PAD];
  __shared__ __bf16 sBh[128 * GT_PAD], sBl[128 * GT_PAD];
  const int tid = threadIdx.x;
  const int lane = tid & 63;
  const int wid = tid >> 6;
  const int wr = wid >> 1, wc = wid & 1;
  const int mBase = blockIdx.y * 128;
  const int nBase = blockIdx.x * 128;

  fv4 acc[4][4] = {};

  const int arowRd = wr * 64 + (lane & 15);
  const int browRd = wc * 64 + (lane & 15);
  const int koff = (lane >> 4) << 3;

  const int srow0 = tid >> 2, srow1 = (256 + tid) >> 2, sch = tid & 3;
  const int ldo0 = srow0 * GT_PAD + sch * 8;
  const int ldo1 = srow1 * GT_PAD + sch * 8;

  u32v4 pa0[2], pa1[2], pb0[2], pb1[2];
  auto LOADK = [&](int k0) {
    const long ga0 = (long)(mBase + srow0) * K + k0 + sch * 8;
    const long ga1 = (long)(mBase + srow1) * K + k0 + sch * 8;
    const long gb0 = (long)(nBase + srow0) * K + k0 + sch * 8;
    const long gb1 = (long)(nBase + srow1) * K + k0 + sch * 8;
    pa0[0] = *(const u32v4*)&Ap[ga0]; pa0[1] = *(const u32v4*)&Ap[ga0 + 4];
    pa1[0] = *(const u32v4*)&Ap[ga1]; pa1[1] = *(const u32v4*)&Ap[ga1 + 4];
    pb0[0] = *(const u32v4*)&Bp[gb0]; pb0[1] = *(const u32v4*)&Bp[gb0 + 4];
    pb1[0] = *(const u32v4*)&Bp[gb1]; pb1[1] = *(const u32v4*)&Bp[gb1 + 4];
  };
  LOADK(0);

  for (int k0 = 0; k0 < K; k0 += 32) {
    __syncthreads();
    {
      u16v8 hi8, lo8;
      if (ASPLIT) split8((const unsigned*)pa0, hi8, lo8);
      else unpack8(pa0[0], pa0[1], hi8, lo8);
      *(u16v8*)&sAh[ldo0] = hi8; *(u16v8*)&sAl[ldo0] = lo8;
      if (ASPLIT) split8((const unsigned*)pa1, hi8, lo8);
      else unpack8(pa1[0], pa1[1], hi8, lo8);
      *(u16v8*)&sAh[ldo1] = hi8; *(u16v8*)&sAl[ldo1] = lo8;
      unpack8(pb0[0], pb0[1], hi8, lo8);
      *(u16v8*)&sBh[ldo0] = hi8; *(u16v8*)&sBl[ldo0] = lo8;
      unpack8(pb1[0], pb1[1], hi8, lo8);
      *(u16v8*)&sBh[ldo1] = hi8; *(u16v8*)&sBl[ldo1] = lo8;
    }
    if (k0 + 32 < K) LOADK(k0 + 32);  // T14: latency hides under barrier+MFMA
    __syncthreads();
    bfv8 fah[4], fal[4], fbh[4], fbl[4];
#pragma unroll
    for (int i = 0; i < 4; ++i) {
      fah[i] = *(const bfv8*)&sAh[(arowRd + i * 16) * GT_PAD + koff];
      fal[i] = *(const bfv8*)&sAl[(arowRd + i * 16) * GT_PAD + koff];
      fbh[i] = *(const bfv8*)&sBh[(browRd + i * 16) * GT_PAD + koff];
      fbl[i] = *(const bfv8*)&sBl[(browRd + i * 16) * GT_PAD + koff];
    }
#pragma unroll
    for (int i = 0; i < 4; ++i)
#pragma unroll
      for (int j = 0; j < 4; ++j) {
        acc[i][j] = __builtin_amdgcn_mfma_f32_16x16x32_bf16(fah[i], fbh[j], acc[i][j], 0, 0, 0);
        acc[i][j] = __builtin_amdgcn_mfma_f32_16x16x32_bf16(fah[i], fbl[j], acc[i][j], 0, 0, 0);
        acc[i][j] = __builtin_amdgcn_mfma_f32_16x16x32_bf16(fal[i], fbh[j], acc[i][j], 0, 0, 0);
      }
  }

  // C/D layout (verified m89): col = lane&15, row = 4*(lane>>4) + reg
  const int crow0 = mBase + wr * 64 + ((lane >> 4) << 2);
  const int ccol0 = nBase + wc * 64 + (lane & 15);
  if (Cp) {
#pragma unroll
    for (int j = 0; j < 4; ++j) {
      const int col = ccol0 + j * 16;
#pragma unroll
      for (int i = 0; i < 4; ++i) {
        const long rb = (long)(crow0 + i * 16) * N + col;
#pragma unroll
        for (int r = 0; r < 4; ++r)
          Cp[rb + (long)r * N] = packbf2(acc[i][j][r]);
      }
    }
  } else {
#pragma unroll
    for (int j = 0; j < 4; ++j) {
      const int col = ccol0 + j * 16;
      const float bv = bias ? bias[col] : 0.f;
#pragma unroll
      for (int i = 0; i < 4; ++i) {
        const long rb = (long)(crow0 + i * 16) * N + col;
#pragma unroll
        for (int r = 0; r < 4; ++r)
          C[rb + (long)r * N] = acc[i][j][r] + bv;
      }
    }
  }
}

// ---------------- per-(b,seg,h) outer products, MFMA-ized, swizzled LDS ----------------
__global__ __launch_bounds__(256) void seg_outer_mfma(
    const unsigned* __restrict__ Kp, const unsigned* __restrict__ Vp,
    float* __restrict__ U, float* __restrict__ Zs) {
  __shared__ __bf16 sAh[64 * 64], sAl[64 * 64];  // akT [d][s]
  __shared__ __bf16 sVh[64 * 64], sVl[64 * 64];  // vT  [e][s]
  __shared__ float sZf[64];
  const int bid = blockIdx.x;            // b*256 + seg*16 + h
  const int b = bid >> 8, seg = (bid >> 4) & 15, h = bid & 15;
  const int tid = threadIdx.x;
  const int lane = tid & 63, w = tid >> 6;
  const int g = lane >> 4, ln16 = lane & 15;
  const long base = ((long)b * L_DIM + (long)seg * SEG_S) * D_DIM + h * 64;

  if (tid < 64) sZf[tid] = 0.f;
  fv4 acc[4] = {};
  float zacc = 0.f;
  const int strow = tid & 63;
  const int sg0 = (tid >> 6) * 16;
  const int wsw = (strow & 7) << 3;
  const int rsw = (ln16 & 7) << 3;

  for (int c = 0; c < 8; ++c) {
    __syncthreads();
#pragma unroll
    for (int jj = 0; jj < 2; ++jj) {
      u16v8 ah, al, vh, vl;
#pragma unroll
      for (int i = 0; i < 8; ++i) {
        const long gidx = base + (long)(c * 64 + sg0 + jj * 8 + i) * D_DIM + strow;
        const unsigned ku = Kp[gidx];
        const unsigned vu = Vp[gidx];
        const float kv = up_hi(ku) + up_lo(ku);
        const float a = kv > 0.f ? kv + 1.f : __expf(kv);
        zacc += a;
        const unsigned short hb = f2bf(a);
        ah[i] = hb;
        al[i] = f2bf(a - bf2f(hb));
        vh[i] = (unsigned short)(vu & 0xffffu);
        vl[i] = (unsigned short)(vu >> 16);
      }
      const int col = (sg0 + jj * 8) ^ wsw;
      *(u16v8*)&sAh[strow * 64 + col] = ah;
      *(u16v8*)&sAl[strow * 64 + col] = al;
      *(u16v8*)&sVh[strow * 64 + col] = vh;
      *(u16v8*)&sVl[strow * 64 + col] = vl;
    }
    __syncthreads();
#pragma unroll
    for (int kf = 0; kf < 2; ++kf) {
      const int so = (kf * 32 + g * 8) ^ rsw;
      bfv8 aH = *(const bfv8*)&sAh[(w * 16 + ln16) * 64 + so];
      bfv8 aL = *(const bfv8*)&sAl[(w * 16 + ln16) * 64 + so];
#pragma unroll
      for (int et = 0; et < 4; ++et) {
        bfv8 bH = *(const bfv8*)&sVh[(et * 16 + ln16) * 64 + so];
        bfv8 bL = *(const bfv8*)&sVl[(et * 16 + ln16) * 64 + so];
        acc[et] = __builtin_amdgcn_mfma_f32_16x16x32_bf16(aH, bH, acc[et], 0, 0, 0);
        acc[et] = __builtin_amdgcn_mfma_f32_16x16x32_bf16(aH, bL, acc[et], 0, 0, 0);
        acc[et] = __builtin_amdgcn_mfma_f32_16x16x32_bf16(aL, bH, acc[et], 0, 0, 0);
      }
    }
  }
  atomicAdd(&sZf[strow], zacc);
  __syncthreads();

  const long ub = (long)bid * 4096;
#pragma unroll
  for (int et = 0; et < 4; ++et)
#pragma unroll
    for (int r = 0; r < 4; ++r)
      U[ub + (long)(w * 16 + g * 4 + r) * 64 + et * 16 + ln16] = acc[et][r];
  if (tid < 64) Zs[(long)bid * 64 + tid] = sZf[tid];
}

// ---------------- exclusive prefix over segments (per b,h) ----------------
__global__ __launch_bounds__(256) void seg_prefix(
    const float* __restrict__ U, const float* __restrict__ Zs,
    float* __restrict__ Mem, float* __restrict__ Zp) {
  const int bh = blockIdx.x;  // b*16 + h
  const int b = bh >> 4, h = bh & 15;
  const int jc = blockIdx.y;  // 0..7
  const int tid = threadIdx.x;
  for (int j = jc * 512 + tid; j < jc * 512 + 512; j += 256) {
    float run = 0.f;
#pragma unroll
    for (int t = 0; t < NSEG; ++t) {
      const long idx = ((long)(b * 256 + t * 16 + h)) * 4096 + j;
      Mem[idx] = run;
      run += U[idx];
    }
  }
  if (jc == 0 && tid < 64) {
    float run = 0.f;
#pragma unroll
    for (int t = 0; t < NSEG; ++t) {
      const long idx = ((long)(b * 256 + t * 16 + h)) * 64 + tid;
      Zp[idx] = run;
      run += Zs[idx];
    }
  }
}

// ---------------- MFMA segment attention: per-batch, in-place att over Q ----------------
// launch_bounds (512,4): VGPR cap 128, kernel uses ~60 -> NO spill (round-8 lesson).
// Qp/Op alias in-place: Q register-loaded before any store; h-columns disjoint per block.
__global__ __launch_bounds__(512, 4) void attn_seg_mfma(
    const unsigned* Qp, const unsigned* __restrict__ Kp,
    const unsigned* __restrict__ Vp, const int* __restrict__ mask,
    const float* __restrict__ Mem, const float* __restrict__ Zp,
    const float* __restrict__ betas, unsigned* Op, int b) {
  __shared__ __bf16 sKh[64 * 72], sKl[64 * 72];  // K chunk [key][d]; later Mem^T [e][d]
  __shared__ __bf16 sVTh[64 * 64];               // V^T [e][key], swizzled, hi only
  __shared__ __bf16 sP[8][16 * 72];              // per-wave P (bf16) [q][key]
  __shared__ float sMadd[64], sZ[64], sGate[64];

  // T1: bijective XCD swizzle (nwg = 1024, 1024%8==0): the 4 qblks of one
  // (seg,h) (sharing K/V) land on the same XCD.
  const int bx = (blockIdx.x & 7) * 128 + (blockIdx.x >> 3);
  const int qblk = bx & 3, h = (bx >> 2) & 15, seg = bx >> 6;
  const int shb = b * 256 + seg * 16 + h;
  const int tid = threadIdx.x;
  const int lane = tid & 63, w = tid >> 6;
  const int g = lane >> 4, ln16 = lane & 15;
  const int rsw = (ln16 & 7) << 3;

  // ---- Q fragments (16 queries per wave), packed loads ----
  const int qglob = b * L_DIM + seg * SEG_S + qblk * 128 + w * 16 + ln16;
  const long qbase = (long)qglob * D_DIM + h * 64;
  bfv8 qh[2], ql[2];
#pragma unroll
  for (int dt = 0; dt < 2; ++dt) {
    u32v4 a = *(const u32v4*)&Qp[qbase + dt * 32 + g * 8];
    u32v4 bb = *(const u32v4*)&Qp[qbase + dt * 32 + g * 8 + 4];
    u16v8 hi8, lo8;
    unpack8(a, bb, hi8, lo8);
    qh[dt] = __builtin_bit_cast(bfv8, hi8);
    ql[dt] = __builtin_bit_cast(bfv8, lo8);
  }

  fv4 O[4] = {};
  float m_run = -1e30f, l_run = 0.f;
  const long kvbase0 = ((long)b * L_DIM + (long)seg * SEG_S) * D_DIM + h * 64;

  for (int c = 0; c < 8; ++c) {
    __syncthreads();
    // ---- stage K [64 key][64 d]: 512 thr, 8 els each ----
    {
      const int row = tid >> 3, d0 = (tid & 7) * 8;
      const long ga = kvbase0 + (long)(c * 64 + row) * D_DIM + d0;
      u32v4 a = *(const u32v4*)&Kp[ga], bb = *(const u32v4*)&Kp[ga + 4];
      u16v8 hi8, lo8;
      unpack8(a, bb, hi8, lo8);
      *(u16v8*)&sKh[row * 72 + d0] = hi8;
      *(u16v8*)&sKl[row * 72 + d0] = lo8;
    }
    // ---- stage V^T [64 e][64 key], row-per-thread, XOR-swizzled, hi only ----
    {
      const int e = tid & 63, kg = (tid >> 6) * 8;
      u16v8 hv;
#pragma unroll
      for (int j = 0; j < 8; ++j) {
        const unsigned u = Vp[kvbase0 + (long)(c * 64 + kg + j) * D_DIM + e];
        hv[j] = (unsigned short)(u & 0xffffu);
      }
      *(u16v8*)&sVTh[e * 64 + (kg ^ ((e & 7) << 3))] = hv;
    }
    if (tid < 64)
      sMadd[tid] = (mask[b * L_DIM + seg * SEG_S + c * 64 + tid] == 0) ? -1e9f : 0.f;
    __syncthreads();

    fv4 madd[4];
#pragma unroll
    for (int kt = 0; kt < 4; ++kt) madd[kt] = *(const fv4*)&sMadd[kt * 16 + g * 4];

    // ---- S^T = K . Q^T (split 3-product) ----
    fv4 sc[4];
#pragma unroll
    for (int kt = 0; kt < 4; ++kt) {
      const int ro = (kt * 16 + ln16) * 72 + g * 8;
      bfv8 kh0 = *(const bfv8*)&sKh[ro], kh1 = *(const bfv8*)&sKh[ro + 32];
      bfv8 kl0 = *(const bfv8*)&sKl[ro], kl1 = *(const bfv8*)&sKl[ro + 32];
      fv4 s = {};
      s = __builtin_amdgcn_mfma_f32_16x16x32_bf16(kh0, qh[0], s, 0, 0, 0);
      s = __builtin_amdgcn_mfma_f32_16x16x32_bf16(kh1, qh[1], s, 0, 0, 0);
      s = __builtin_amdgcn_mfma_f32_16x16x32_bf16(kh0, ql[0], s, 0, 0, 0);
      s = __builtin_amdgcn_mfma_f32_16x16x32_bf16(kh1, ql[1], s, 0, 0, 0);
      s = __builtin_amdgcn_mfma_f32_16x16x32_bf16(kl0, qh[0], s, 0, 0, 0);
      s = __builtin_amdgcn_mfma_f32_16x16x32_bf16(kl1, qh[1], s, 0, 0, 0);
      sc[kt] = s;
    }
    // ---- online softmax (defer-max THR=8) ----
    float pmax = -3.0e38f;
#pragma unroll
    for (int kt = 0; kt < 4; ++kt)
#pragma unroll
      for (int r = 0; r < 4; ++r) {
        const float v = __builtin_fmaf(sc[kt][r], 0.125f, madd[kt][r]);
        sc[kt][r] = v;
        pmax = fmaxf(pmax, v);
      }
    pmax = fmaxf(pmax, __shfl_xor(pmax, 16));
    pmax = fmaxf(pmax, __shfl_xor(pmax, 32));
    if (pmax > m_run + 8.f) {
      const float resc = __expf(m_run - pmax);
      l_run *= resc;
#pragma unroll
      for (int et = 0; et < 4; ++et)
#pragma unroll
        for (int r = 0; r < 4; ++r) O[et][r] *= resc;
      m_run = pmax;
    }
    float psum = 0.f;
#pragma unroll
    for (int kt = 0; kt < 4; ++kt) {
      u16v4 pv;
#pragma unroll
      for (int r = 0; r < 4; ++r) {
        const unsigned short hb = f2bf(__expf(sc[kt][r] - m_run));
        pv[r] = hb;
        psum += bf2f(hb);
      }
      *(u16v4*)&sP[w][ln16 * 72 + kt * 16 + g * 4] = pv;
    }
    psum += __shfl_xor(psum, 16);
    psum += __shfl_xor(psum, 32);
    l_run += psum;

    bfv8 pf0 = *(const bfv8*)&sP[w][ln16 * 72 + g * 8];
    bfv8 pf1 = *(const bfv8*)&sP[w][ln16 * 72 + 32 + g * 8];
    // ---- O^T += V^T . P (V hi only, swizzled reads) ----
#pragma unroll
    for (int et = 0; et < 4; ++et) {
      const int rb = (et * 16 + ln16) * 64;
      bfv8 vh0 = *(const bfv8*)&sVTh[rb + ((g * 8) ^ rsw)];
      bfv8 vh1 = *(const bfv8*)&sVTh[rb + ((g * 8 + 32) ^ rsw)];
      fv4 o = O[et];
      o = __builtin_amdgcn_mfma_f32_16x16x32_bf16(vh0, pf0, o, 0, 0, 0);
      o = __builtin_amdgcn_mfma_f32_16x16x32_bf16(vh1, pf1, o, 0, 0, 0);
      O[et] = o;
    }
  }

  // ---- memory-read term ----
  __syncthreads();
  {  // stage Mem^T [e][d] into sKh/sKl (fp32 source, once per block)
    const int e2 = (tid & 31) * 2, d4 = (tid >> 5) * 4;
    const float* Memp = Mem + (long)shb * 4096;
    fv2 ld[4];
#pragma unroll
    for (int i = 0; i < 4; ++i) ld[i] = *(const fv2*)&Memp[(d4 + i) * 64 + e2];
#pragma unroll
    for (int je = 0; je < 2; ++je) {
      u16v4 hv, lv;
#pragma unroll
      for (int i = 0; i < 4; ++i) {
        const unsigned short hb = f2bf(ld[i][je]);
        hv[i] = hb;
        lv[i] = f2bf(ld[i][je] - bf2f(hb));
      }
      *(u16v4*)&sKh[(e2 + je) * 72 + d4] = hv;
      *(u16v4*)&sKl[(e2 + je) * 72 + d4] = lv;
    }
  }
  if (tid < 64) {
    sZ[tid] = Zp[(long)shb * 64 + tid];
    sGate[tid] = 1.f / (1.f + __expf(-betas[h * 64 + tid]));
  }
  __syncthreads();

  // aq = elu(q)+1 in-register; denom = aq . z
  float dpart = 0.f;
#pragma unroll
  for (int dt = 0; dt < 2; ++dt) {
    u16v8 ah, al;
#pragma unroll
    for (int j = 0; j < 8; ++j) {
      const float x = (float)qh[dt][j] + (float)ql[dt][j];
      const float a = x > 0.f ? x + 1.f : __expf(x);
      dpart += a * sZ[dt * 32 + g * 8 + j];
      const unsigned short hb = f2bf(a);
      ah[j] = hb;
      al[j] = f2bf(a - bf2f(hb));
    }
    qh[dt] = __builtin_bit_cast(bfv8, ah);
    ql[dt] = __builtin_bit_cast(bfv8, al);
  }
  dpart += __shfl_xor(dpart, 16);
  dpart += __shfl_xor(dpart, 32);
  const float invden = 1.f / (dpart + 1e-9f);
  const float invl = 1.f / l_run;

  const long obase = (long)qglob * D_DIM + h * 64;
#pragma unroll
  for (int et = 0; et < 4; ++et) {
    const int ro = (et * 16 + ln16) * 72 + g * 8;
    bfv8 mh0 = *(const bfv8*)&sKh[ro], mh1 = *(const bfv8*)&sKh[ro + 32];
    bfv8 ml0 = *(const bfv8*)&sKl[ro], ml1 = *(const bfv8*)&sKl[ro + 32];
    fv4 o = {};
    o = __builtin_amdgcn_mfma_f32_16x16x32_bf16(mh0, qh[0], o, 0, 0, 0);
    o = __builtin_amdgcn_mfma_f32_16x16x32_bf16(mh1, qh[1], o, 0, 0, 0);
    o = __builtin_amdgcn_mfma_f32_16x16x32_bf16(mh0, ql[0], o, 0, 0, 0);
    o = __builtin_amdgcn_mfma_f32_16x16x32_bf16(mh1, ql[1], o, 0, 0, 0);
    o = __builtin_amdgcn_mfma_f32_16x16x32_bf16(ml0, qh[0], o, 0, 0, 0);
    o = __builtin_amdgcn_mfma_f32_16x16x32_bf16(ml1, qh[1], o, 0, 0, 0);
    const fv4 gt = *(const fv4*)&sGate[et * 16 + g * 4];
    u32v4 st;
#pragma unroll
    for (int r = 0; r < 4; ++r) {
      const float att = gt[r] * o[r] * invden + (1.f - gt[r]) * O[et][r] * invl;
      st[r] = packbf2(att);
    }
    *(u32v4*)&Op[obase + et * 16 + g * 4] = st;
  }
}

// ---------------- host launch ----------------
extern "C" void kernel_launch(void* const* d_in, const int* in_sizes, int n_in,
                              void* d_out, int out_size, void* d_ws, size_t ws_size,
                              hipStream_t stream) {
  (void)in_sizes; (void)n_in; (void)out_size;
  const float* x     = (const float*)d_in[0];
  const int*   mask  = (const int*)d_in[1];
  const float* wq    = (const float*)d_in[2];
  const float* wk    = (const float*)d_in[3];
  const float* wv    = (const float*)d_in[4];
  const float* wo    = (const float*)d_in[5];
  const float* wob   = (const float*)d_in[6];
  const float* betas = (const float*)d_in[7];
  float* out = (float*)d_out;

  const size_t TOK = (size_t)M_TOK * D_DIM;  // 33.5M elements
  char* ws = (char*)d_ws;
  size_t off = 0;
  auto alloc = [&](size_t bytes) {
    char* p = ws + off;
    off += (bytes + 255) & ~(size_t)255;
    return p;
  };
  unsigned* wsp[4];
  for (int i = 0; i < 4; ++i)
    wsp[i] = (unsigned*)alloc((size_t)D_DIM * D_DIM * 4);  // 4 MiB each
  unsigned* qp = (unsigned*)alloc(TOK * 4);  // 128 MiB
  unsigned* kp = (unsigned*)alloc(TOK * 4);
  unsigned* vp = (unsigned*)alloc(TOK * 4);
  float* U   = (float*)alloc((size_t)B_DIM * NSEG * H_NUM * 4096 * 4);  // 16.8 MiB
  float* Mem = (float*)alloc((size_t)B_DIM * NSEG * H_NUM * 4096 * 4);
  float* Zs  = (float*)alloc((size_t)B_DIM * NSEG * H_NUM * 64 * 4);
  float* Zp  = (float*)alloc((size_t)B_DIM * NSEG * H_NUM * 64 * 4);
  // total ≈ 434 MiB < ws. att output written IN-PLACE over qp.

  if (off > ws_size) return;

  const float* wsrc[4] = {wq, wk, wv, wo};
  for (int i = 0; i < 4; ++i)
    split_pack<<<512, 256, 0, stream>>>(wsrc[i], wsp[i], D_DIM * D_DIM / 4);

  dim3 ggrid(D_DIM / 128, M_TOK / 128);  // 8 x 256 = 2048 blocks
  gemm_bt<1><<<ggrid, 256, 0, stream>>>((const unsigned*)x, wsp[0], nullptr, nullptr,
                                        qp, M_TOK, D_DIM, D_DIM);
  gemm_bt<1><<<ggrid, 256, 0, stream>>>((const unsigned*)x, wsp[1], nullptr, nullptr,
                                        kp, M_TOK, D_DIM, D_DIM);
  gemm_bt<1><<<ggrid, 256, 0, stream>>>((const unsigned*)x, wsp[2], nullptr, nullptr,
                                        vp, M_TOK, D_DIM, D_DIM);

  seg_outer_mfma<<<B_DIM * NSEG * H_NUM, 256, 0, stream>>>(kp, vp, U, Zs);
  seg_prefix<<<dim3(B_DIM * H_NUM, 8), 256, 0, stream>>>(U, Zs, Mem, Zp);

  for (int b = 0; b < B_DIM; ++b)
    attn_seg_mfma<<<NSEG * H_NUM * 4, 512, 0, stream>>>(qp, kp, vp, mask, Mem, Zp,
                                                        betas, qp, b);

  gemm_bt<0><<<ggrid, 256, 0, stream>>>(qp, wsp[3], out, wob, nullptr,
                                        M_TOK, D_DIM, D_DIM);
}

// Round 10
// 1228.438 us; speedup vs baseline: 1.2210x; 1.0314x over previous
//
#include <hip/hip_runtime.h>

typedef float fv2 __attribute__((ext_vector_type(2)));
typedef float fv4 __attribute__((ext_vector_type(4)));
typedef __bf16 bfv8 __attribute__((ext_vector_type(8)));
typedef unsigned short u16v4 __attribute__((ext_vector_type(4)));
typedef unsigned short u16v8 __attribute__((ext_vector_type(8)));
typedef unsigned int u32v2 __attribute__((ext_vector_type(2)));
typedef unsigned int u32v4 __attribute__((ext_vector_type(4)));

#define B_DIM 4
#define L_DIM 8192
#define D_DIM 1024
#define H_NUM 16
#define NSEG 16
#define SEG_S 512
#define M_TOK (B_DIM * L_DIM)  // 32768 rows, all batches fused

__device__ __forceinline__ unsigned short f2bf(float f) {
  unsigned u = __float_as_uint(f);
  u += 0x7fffu + ((u >> 16) & 1u);  // RNE
  return (unsigned short)(u >> 16);
}
__device__ __forceinline__ float bf2f(unsigned short h) {
  return __uint_as_float((unsigned)h << 16);
}
__device__ __forceinline__ unsigned packbf2(float v) {
  unsigned short hb = f2bf(v);
  unsigned short lb = f2bf(v - bf2f(hb));
  return (unsigned)hb | ((unsigned)lb << 16);
}
__device__ __forceinline__ float up_hi(unsigned u) { return __uint_as_float(u << 16); }
__device__ __forceinline__ float up_lo(unsigned u) { return __uint_as_float(u & 0xffff0000u); }

// barrier that drains ONLY LDS ops — leaves global prefetch in flight (T4).
// __syncthreads() would emit s_waitcnt vmcnt(0) and kill the T14 overlap.
__device__ __forceinline__ void barrier_lgkm() {
  asm volatile("s_waitcnt lgkmcnt(0)" ::: "memory");
  __builtin_amdgcn_s_barrier();
}

// unpack 8 packed elements (2 x u32v4) -> u16v8 of 8 hi-bf16 and 8 lo-bf16
__device__ __forceinline__ void unpack8(u32v4 a, u32v4 b, u16v8& hi8, u16v8& lo8) {
  u32v4 hi, lo;
  hi[0] = __builtin_amdgcn_perm(a[1], a[0], 0x05040100u);
  hi[1] = __builtin_amdgcn_perm(a[3], a[2], 0x05040100u);
  hi[2] = __builtin_amdgcn_perm(b[1], b[0], 0x05040100u);
  hi[3] = __builtin_amdgcn_perm(b[3], b[2], 0x05040100u);
  lo[0] = __builtin_amdgcn_perm(a[1], a[0], 0x07060302u);
  lo[1] = __builtin_amdgcn_perm(a[3], a[2], 0x07060302u);
  lo[2] = __builtin_amdgcn_perm(b[1], b[0], 0x07060302u);
  lo[3] = __builtin_amdgcn_perm(b[3], b[2], 0x07060302u);
  hi8 = __builtin_bit_cast(u16v8, hi);
  lo8 = __builtin_bit_cast(u16v8, lo);
}
// split 8 fp32 (as raw u32x8) -> hi/lo bf16 planes
__device__ __forceinline__ void split8(const unsigned* pr, u16v8& hi8, u16v8& lo8) {
#pragma unroll
  for (int j = 0; j < 8; ++j) {
    const float v = __uint_as_float(pr[j]);
    const unsigned short hb = f2bf(v);
    hi8[j] = hb;
    lo8[j] = f2bf(v - bf2f(hb));
  }
}

// ---------------- fp32 -> packed (hi|lo<<16) split (weights only) ----------------
__global__ __launch_bounds__(256) void split_pack(
    const float* __restrict__ in, unsigned* __restrict__ outp, int n4) {
  int i = blockIdx.x * 256 + threadIdx.x;
  const int stride = gridDim.x * 256;
  for (; i < n4; i += stride) {
    fv4 v = reinterpret_cast<const fv4*>(in)[i];
    u32v4 p;
#pragma unroll
    for (int j = 0; j < 4; ++j) p[j] = packbf2(v[j]);
    reinterpret_cast<u32v4*>(outp)[i] = p;
  }
}

// ---------------- C[M,N] = A @ B^T, split-bf16 3-product MFMA ----------------
// ASPLIT=1: A is fp32 (split fused into staging). ASPLIT=0: A is packed u32.
// 1-D grid, T1 XCD swizzle: 8 blocks sharing one A M-panel land on ONE XCD.
#define GT_PAD 40
template <int ASPLIT>
__global__ __launch_bounds__(256, 3) void gemm_bt(
    const unsigned* __restrict__ Ap, const unsigned* __restrict__ Bp,
    float* __restrict__ C, const float* __restrict__ bias,
    unsigned* __restrict__ Cp, int M, int N, int K) {
  __shared__ __bf16 sAh[128 * GT_PAD], sAl[128 * GT_PAD];
  __shared__ __bf16 sBh[128 * GT_PAD], sBl[128 * GT_PAD];
  const int tid = threadIdx.x;
  const int lane = tid & 63;
  const int wid = tid >> 6;
  const int wr = wid >> 1, wc = wid & 1;

  // XCD swizzle decode: hw%8 = XCD id (round-robin dispatch). All 8 N-tiles of
  // one M-panel get the same hw%8 -> same XCD -> A panel fetched once per L2.
  const int hw = blockIdx.x;
  const int xcd = hw & 7;
  const int rem = hw >> 3;
  const int ntile = rem & 7;          // 0..7  (N/128)
  const int yhi = rem >> 3;           // 0..31
  const int mtile = yhi * 8 + xcd;    // 0..255 (M/128), bijective
  const int mBase = mtile * 128;
  const int nBase = ntile * 128;

  fv4 acc[4][4] = {};

  const int arowRd = wr * 64 + (lane & 15);
  const int browRd = wc * 64 + (lane & 15);
  const int koff = (lane >> 4) << 3;

  const int srow0 = tid >> 2, srow1 = (256 + tid) >> 2, sch = tid & 3;
  const int ldo0 = srow0 * GT_PAD + sch * 8;
  const int ldo1 = srow1 * GT_PAD + sch * 8;

  u32v4 pa0[2], pa1[2], pb0[2], pb1[2];
  auto LOADK = [&](int k0) {
    const long ga0 = (long)(mBase + srow0) * K + k0 + sch * 8;
    const long ga1 = (long)(mBase + srow1) * K + k0 + sch * 8;
    const long gb0 = (long)(nBase + srow0) * K + k0 + sch * 8;
    const long gb1 = (long)(nBase + srow1) * K + k0 + sch * 8;
    pa0[0] = *(const u32v4*)&Ap[ga0]; pa0[1] = *(const u32v4*)&Ap[ga0 + 4];
    pa1[0] = *(const u32v4*)&Ap[ga1]; pa1[1] = *(const u32v4*)&Ap[ga1 + 4];
    pb0[0] = *(const u32v4*)&Bp[gb0]; pb0[1] = *(const u32v4*)&Bp[gb0 + 4];
    pb1[0] = *(const u32v4*)&Bp[gb1]; pb1[1] = *(const u32v4*)&Bp[gb1 + 4];
  };
  LOADK(0);

  for (int k0 = 0; k0 < K; k0 += 32) {
    barrier_lgkm();  // frag reads of prev step retired; vmcnt NOT drained
    {
      u16v8 hi8, lo8;
      if (ASPLIT) split8((const unsigned*)pa0, hi8, lo8);
      else unpack8(pa0[0], pa0[1], hi8, lo8);
      *(u16v8*)&sAh[ldo0] = hi8; *(u16v8*)&sAl[ldo0] = lo8;
      if (ASPLIT) split8((const unsigned*)pa1, hi8, lo8);
      else unpack8(pa1[0], pa1[1], hi8, lo8);
      *(u16v8*)&sAh[ldo1] = hi8; *(u16v8*)&sAl[ldo1] = lo8;
      unpack8(pb0[0], pb0[1], hi8, lo8);
      *(u16v8*)&sBh[ldo0] = hi8; *(u16v8*)&sBl[ldo0] = lo8;
      unpack8(pb1[0], pb1[1], hi8, lo8);
      *(u16v8*)&sBh[ldo1] = hi8; *(u16v8*)&sBl[ldo1] = lo8;
    }
    if (k0 + 32 < K) LOADK(k0 + 32);  // stays in flight across the barrier (T14/T4)
    barrier_lgkm();  // ds_writes visible; prefetch still in flight
    bfv8 fah[4], fal[4], fbh[4], fbl[4];
#pragma unroll
    for (int i = 0; i < 4; ++i) {
      fah[i] = *(const bfv8*)&sAh[(arowRd + i * 16) * GT_PAD + koff];
      fal[i] = *(const bfv8*)&sAl[(arowRd + i * 16) * GT_PAD + koff];
      fbh[i] = *(const bfv8*)&sBh[(browRd + i * 16) * GT_PAD + koff];
      fbl[i] = *(const bfv8*)&sBl[(browRd + i * 16) * GT_PAD + koff];
    }
#pragma unroll
    for (int i = 0; i < 4; ++i)
#pragma unroll
      for (int j = 0; j < 4; ++j) {
        acc[i][j] = __builtin_amdgcn_mfma_f32_16x16x32_bf16(fah[i], fbh[j], acc[i][j], 0, 0, 0);
        acc[i][j] = __builtin_amdgcn_mfma_f32_16x16x32_bf16(fah[i], fbl[j], acc[i][j], 0, 0, 0);
        acc[i][j] = __builtin_amdgcn_mfma_f32_16x16x32_bf16(fal[i], fbh[j], acc[i][j], 0, 0, 0);
      }
  }

  // C/D layout (verified m89): col = lane&15, row = 4*(lane>>4) + reg
  const int crow0 = mBase + wr * 64 + ((lane >> 4) << 2);
  const int ccol0 = nBase + wc * 64 + (lane & 15);
  if (Cp) {
#pragma unroll
    for (int j = 0; j < 4; ++j) {
      const int col = ccol0 + j * 16;
#pragma unroll
      for (int i = 0; i < 4; ++i) {
        const long rb = (long)(crow0 + i * 16) * N + col;
#pragma unroll
        for (int r = 0; r < 4; ++r)
          Cp[rb + (long)r * N] = packbf2(acc[i][j][r]);
      }
    }
  } else {
#pragma unroll
    for (int j = 0; j < 4; ++j) {
      const int col = ccol0 + j * 16;
      const float bv = bias ? bias[col] : 0.f;
#pragma unroll
      for (int i = 0; i < 4; ++i) {
        const long rb = (long)(crow0 + i * 16) * N + col;
#pragma unroll
        for (int r = 0; r < 4; ++r)
          C[rb + (long)r * N] = acc[i][j][r] + bv;
      }
    }
  }
}

// ---------------- per-(b,seg,h) outer products, MFMA-ized, swizzled LDS ----------------
__global__ __launch_bounds__(256) void seg_outer_mfma(
    const unsigned* __restrict__ Kp, const unsigned* __restrict__ Vp,
    float* __restrict__ U, float* __restrict__ Zs) {
  __shared__ __bf16 sAh[64 * 64], sAl[64 * 64];  // akT [d][s]
  __shared__ __bf16 sVh[64 * 64], sVl[64 * 64];  // vT  [e][s]
  __shared__ float sZf[64];
  const int bid = blockIdx.x;            // b*256 + seg*16 + h
  const int b = bid >> 8, seg = (bid >> 4) & 15, h = bid & 15;
  const int tid = threadIdx.x;
  const int lane = tid & 63, w = tid >> 6;
  const int g = lane >> 4, ln16 = lane & 15;
  const long base = ((long)b * L_DIM + (long)seg * SEG_S) * D_DIM + h * 64;

  if (tid < 64) sZf[tid] = 0.f;
  fv4 acc[4] = {};
  float zacc = 0.f;
  const int strow = tid & 63;
  const int sg0 = (tid >> 6) * 16;
  const int wsw = (strow & 7) << 3;
  const int rsw = (ln16 & 7) << 3;

  for (int c = 0; c < 8; ++c) {
    __syncthreads();
#pragma unroll
    for (int jj = 0; jj < 2; ++jj) {
      u16v8 ah, al, vh, vl;
#pragma unroll
      for (int i = 0; i < 8; ++i) {
        const long gidx = base + (long)(c * 64 + sg0 + jj * 8 + i) * D_DIM + strow;
        const unsigned ku = Kp[gidx];
        const unsigned vu = Vp[gidx];
        const float kv = up_hi(ku) + up_lo(ku);
        const float a = kv > 0.f ? kv + 1.f : __expf(kv);
        zacc += a;
        const unsigned short hb = f2bf(a);
        ah[i] = hb;
        al[i] = f2bf(a - bf2f(hb));
        vh[i] = (unsigned short)(vu & 0xffffu);
        vl[i] = (unsigned short)(vu >> 16);
      }
      const int col = (sg0 + jj * 8) ^ wsw;
      *(u16v8*)&sAh[strow * 64 + col] = ah;
      *(u16v8*)&sAl[strow * 64 + col] = al;
      *(u16v8*)&sVh[strow * 64 + col] = vh;
      *(u16v8*)&sVl[strow * 64 + col] = vl;
    }
    __syncthreads();
#pragma unroll
    for (int kf = 0; kf < 2; ++kf) {
      const int so = (kf * 32 + g * 8) ^ rsw;
      bfv8 aH = *(const bfv8*)&sAh[(w * 16 + ln16) * 64 + so];
      bfv8 aL = *(const bfv8*)&sAl[(w * 16 + ln16) * 64 + so];
#pragma unroll
      for (int et = 0; et < 4; ++et) {
        bfv8 bH = *(const bfv8*)&sVh[(et * 16 + ln16) * 64 + so];
        bfv8 bL = *(const bfv8*)&sVl[(et * 16 + ln16) * 64 + so];
        acc[et] = __builtin_amdgcn_mfma_f32_16x16x32_bf16(aH, bH, acc[et], 0, 0, 0);
        acc[et] = __builtin_amdgcn_mfma_f32_16x16x32_bf16(aH, bL, acc[et], 0, 0, 0);
        acc[et] = __builtin_amdgcn_mfma_f32_16x16x32_bf16(aL, bH, acc[et], 0, 0, 0);
      }
    }
  }
  atomicAdd(&sZf[strow], zacc);
  __syncthreads();

  const long ub = (long)bid * 4096;
#pragma unroll
  for (int et = 0; et < 4; ++et)
#pragma unroll
    for (int r = 0; r < 4; ++r)
      U[ub + (long)(w * 16 + g * 4 + r) * 64 + et * 16 + ln16] = acc[et][r];
  if (tid < 64) Zs[(long)bid * 64 + tid] = sZf[tid];
}

// ---------------- exclusive prefix over segments (per b,h) ----------------
__global__ __launch_bounds__(256) void seg_prefix(
    const float* __restrict__ U, const float* __restrict__ Zs,
    float* __restrict__ Mem, float* __restrict__ Zp) {
  const int bh = blockIdx.x;  // b*16 + h
  const int b = bh >> 4, h = bh & 15;
  const int jc = blockIdx.y;  // 0..7
  const int tid = threadIdx.x;
  for (int j = jc * 512 + tid; j < jc * 512 + 512; j += 256) {
    float run = 0.f;
#pragma unroll
    for (int t = 0; t < NSEG; ++t) {
      const long idx = ((long)(b * 256 + t * 16 + h)) * 4096 + j;
      Mem[idx] = run;
      run += U[idx];
    }
  }
  if (jc == 0 && tid < 64) {
    float run = 0.f;
#pragma unroll
    for (int t = 0; t < NSEG; ++t) {
      const long idx = ((long)(b * 256 + t * 16 + h)) * 64 + tid;
      Zp[idx] = run;
      run += Zs[idx];
    }
  }
}

// ---------------- MFMA segment attention: per-batch, in-place att over Q ----------------
__global__ __launch_bounds__(512, 4) void attn_seg_mfma(
    const unsigned* Qp, const unsigned* __restrict__ Kp,
    const unsigned* __restrict__ Vp, const int* __restrict__ mask,
    const float* __restrict__ Mem, const float* __restrict__ Zp,
    const float* __restrict__ betas, unsigned* Op, int b) {
  __shared__ __bf16 sKh[64 * 72], sKl[64 * 72];  // K chunk [key][d]; later Mem^T [e][d]
  __shared__ __bf16 sVTh[64 * 64];               // V^T [e][key], swizzled, hi only
  __shared__ __bf16 sP[8][16 * 72];              // per-wave P (bf16) [q][key]
  __shared__ float sMadd[64], sZ[64], sGate[64];

  const int bx = (blockIdx.x & 7) * 128 + (blockIdx.x >> 3);
  const int qblk = bx & 3, h = (bx >> 2) & 15, seg = bx >> 6;
  const int shb = b * 256 + seg * 16 + h;
  const int tid = threadIdx.x;
  const int lane = tid & 63, w = tid >> 6;
  const int g = lane >> 4, ln16 = lane & 15;
  const int rsw = (ln16 & 7) << 3;

  const int qglob = b * L_DIM + seg * SEG_S + qblk * 128 + w * 16 + ln16;
  const long qbase = (long)qglob * D_DIM + h * 64;
  bfv8 qh[2], ql[2];
#pragma unroll
  for (int dt = 0; dt < 2; ++dt) {
    u32v4 a = *(const u32v4*)&Qp[qbase + dt * 32 + g * 8];
    u32v4 bb = *(const u32v4*)&Qp[qbase + dt * 32 + g * 8 + 4];
    u16v8 hi8, lo8;
    unpack8(a, bb, hi8, lo8);
    qh[dt] = __builtin_bit_cast(bfv8, hi8);
    ql[dt] = __builtin_bit_cast(bfv8, lo8);
  }

  fv4 O[4] = {};
  float m_run = -1e30f, l_run = 0.f;
  const long kvbase0 = ((long)b * L_DIM + (long)seg * SEG_S) * D_DIM + h * 64;

  for (int c = 0; c < 8; ++c) {
    __syncthreads();
    {
      const int row = tid >> 3, d0 = (tid & 7) * 8;
      const long ga = kvbase0 + (long)(c * 64 + row) * D_DIM + d0;
      u32v4 a = *(const u32v4*)&Kp[ga], bb = *(const u32v4*)&Kp[ga + 4];
      u16v8 hi8, lo8;
      unpack8(a, bb, hi8, lo8);
      *(u16v8*)&sKh[row * 72 + d0] = hi8;
      *(u16v8*)&sKl[row * 72 + d0] = lo8;
    }
    {
      const int e = tid & 63, kg = (tid >> 6) * 8;
      u16v8 hv;
#pragma unroll
      for (int j = 0; j < 8; ++j) {
        const unsigned u = Vp[kvbase0 + (long)(c * 64 + kg + j) * D_DIM + e];
        hv[j] = (unsigned short)(u & 0xffffu);
      }
      *(u16v8*)&sVTh[e * 64 + (kg ^ ((e & 7) << 3))] = hv;
    }
    if (tid < 64)
      sMadd[tid] = (mask[b * L_DIM + seg * SEG_S + c * 64 + tid] == 0) ? -1e9f : 0.f;
    __syncthreads();

    fv4 madd[4];
#pragma unroll
    for (int kt = 0; kt < 4; ++kt) madd[kt] = *(const fv4*)&sMadd[kt * 16 + g * 4];

    fv4 sc[4];
#pragma unroll
    for (int kt = 0; kt < 4; ++kt) {
      const int ro = (kt * 16 + ln16) * 72 + g * 8;
      bfv8 kh0 = *(const bfv8*)&sKh[ro], kh1 = *(const bfv8*)&sKh[ro + 32];
      bfv8 kl0 = *(const bfv8*)&sKl[ro], kl1 = *(const bfv8*)&sKl[ro + 32];
      fv4 s = {};
      s = __builtin_amdgcn_mfma_f32_16x16x32_bf16(kh0, qh[0], s, 0, 0, 0);
      s = __builtin_amdgcn_mfma_f32_16x16x32_bf16(kh1, qh[1], s, 0, 0, 0);
      s = __builtin_amdgcn_mfma_f32_16x16x32_bf16(kh0, ql[0], s, 0, 0, 0);
      s = __builtin_amdgcn_mfma_f32_16x16x32_bf16(kh1, ql[1], s, 0, 0, 0);
      s = __builtin_amdgcn_mfma_f32_16x16x32_bf16(kl0, qh[0], s, 0, 0, 0);
      s = __builtin_amdgcn_mfma_f32_16x16x32_bf16(kl1, qh[1], s, 0, 0, 0);
      sc[kt] = s;
    }
    float pmax = -3.0e38f;
#pragma unroll
    for (int kt = 0; kt < 4; ++kt)
#pragma unroll
      for (int r = 0; r < 4; ++r) {
        const float v = __builtin_fmaf(sc[kt][r], 0.125f, madd[kt][r]);
        sc[kt][r] = v;
        pmax = fmaxf(pmax, v);
      }
    pmax = fmaxf(pmax, __shfl_xor(pmax, 16));
    pmax = fmaxf(pmax, __shfl_xor(pmax, 32));
    if (pmax > m_run + 8.f) {
      const float resc = __expf(m_run - pmax);
      l_run *= resc;
#pragma unroll
      for (int et = 0; et < 4; ++et)
#pragma unroll
        for (int r = 0; r < 4; ++r) O[et][r] *= resc;
      m_run = pmax;
    }
    float psum = 0.f;
#pragma unroll
    for (int kt = 0; kt < 4; ++kt) {
      u16v4 pv;
#pragma unroll
      for (int r = 0; r < 4; ++r) {
        const unsigned short hb = f2bf(__expf(sc[kt][r] - m_run));
        pv[r] = hb;
        psum += bf2f(hb);
      }
      *(u16v4*)&sP[w][ln16 * 72 + kt * 16 + g * 4] = pv;
    }
    psum += __shfl_xor(psum, 16);
    psum += __shfl_xor(psum, 32);
    l_run += psum;

    bfv8 pf0 = *(const bfv8*)&sP[w][ln16 * 72 + g * 8];
    bfv8 pf1 = *(const bfv8*)&sP[w][ln16 * 72 + 32 + g * 8];
#pragma unroll
    for (int et = 0; et < 4; ++et) {
      const int rb = (et * 16 + ln16) * 64;
      bfv8 vh0 = *(const bfv8*)&sVTh[rb + ((g * 8) ^ rsw)];
      bfv8 vh1 = *(const bfv8*)&sVTh[rb + ((g * 8 + 32) ^ rsw)];
      fv4 o = O[et];
      o = __builtin_amdgcn_mfma_f32_16x16x32_bf16(vh0, pf0, o, 0, 0, 0);
      o = __builtin_amdgcn_mfma_f32_16x16x32_bf16(vh1, pf1, o, 0, 0, 0);
      O[et] = o;
    }
  }

  __syncthreads();
  {
    const int e2 = (tid & 31) * 2, d4 = (tid >> 5) * 4;
    const float* Memp = Mem + (long)shb * 4096;
    fv2 ld[4];
#pragma unroll
    for (int i = 0; i < 4; ++i) ld[i] = *(const fv2*)&Memp[(d4 + i) * 64 + e2];
#pragma unroll
    for (int je = 0; je < 2; ++je) {
      u16v4 hv, lv;
#pragma unroll
      for (int i = 0; i < 4; ++i) {
        const unsigned short hb = f2bf(ld[i][je]);
        hv[i] = hb;
        lv[i] = f2bf(ld[i][je] - bf2f(hb));
      }
      *(u16v4*)&sKh[(e2 + je) * 72 + d4] = hv;
      *(u16v4*)&sKl[(e2 + je) * 72 + d4] = lv;
    }
  }
  if (tid < 64) {
    sZ[tid] = Zp[(long)shb * 64 + tid];
    sGate[tid] = 1.f / (1.f + __expf(-betas[h * 64 + tid]));
  }
  __syncthreads();

  float dpart = 0.f;
#pragma unroll
  for (int dt = 0; dt < 2; ++dt) {
    u16v8 ah, al;
#pragma unroll
    for (int j = 0; j < 8; ++j) {
      const float x = (float)qh[dt][j] + (float)ql[dt][j];
      const float a = x > 0.f ? x + 1.f : __expf(x);
      dpart += a * sZ[dt * 32 + g * 8 + j];
      const unsigned short hb = f2bf(a);
      ah[j] = hb;
      al[j] = f2bf(a - bf2f(hb));
    }
    qh[dt] = __builtin_bit_cast(bfv8, ah);
    ql[dt] = __builtin_bit_cast(bfv8, al);
  }
  dpart += __shfl_xor(dpart, 16);
  dpart += __shfl_xor(dpart, 32);
  const float invden = 1.f / (dpart + 1e-9f);
  const float invl = 1.f / l_run;

  const long obase = (long)qglob * D_DIM + h * 64;
#pragma unroll
  for (int et = 0; et < 4; ++et) {
    const int ro = (et * 16 + ln16) * 72 + g * 8;
    bfv8 mh0 = *(const bfv8*)&sKh[ro], mh1 = *(const bfv8*)&sKh[ro + 32];
    bfv8 ml0 = *(const bfv8*)&sKl[ro], ml1 = *(const bfv8*)&sKl[ro + 32];
    fv4 o = {};
    o = __builtin_amdgcn_mfma_f32_16x16x32_bf16(mh0, qh[0], o, 0, 0, 0);
    o = __builtin_amdgcn_mfma_f32_16x16x32_bf16(mh1, qh[1], o, 0, 0, 0);
    o = __builtin_amdgcn_mfma_f32_16x16x32_bf16(mh0, ql[0], o, 0, 0, 0);
    o = __builtin_amdgcn_mfma_f32_16x16x32_bf16(mh1, ql[1], o, 0, 0, 0);
    o = __builtin_amdgcn_mfma_f32_16x16x32_bf16(ml0, qh[0], o, 0, 0, 0);
    o = __builtin_amdgcn_mfma_f32_16x16x32_bf16(ml1, qh[1], o, 0, 0, 0);
    const fv4 gt = *(const fv4*)&sGate[et * 16 + g * 4];
    u32v4 st;
#pragma unroll
    for (int r = 0; r < 4; ++r) {
      const float att = gt[r] * o[r] * invden + (1.f - gt[r]) * O[et][r] * invl;
      st[r] = packbf2(att);
    }
    *(u32v4*)&Op[obase + et * 16 + g * 4] = st;
  }
}

// ---------------- host launch ----------------
extern "C" void kernel_launch(void* const* d_in, const int* in_sizes, int n_in,
                              void* d_out, int out_size, void* d_ws, size_t ws_size,
                              hipStream_t stream) {
  (void)in_sizes; (void)n_in; (void)out_size;
  const float* x     = (const float*)d_in[0];
  const int*   mask  = (const int*)d_in[1];
  const float* wq    = (const float*)d_in[2];
  const float* wk    = (const float*)d_in[3];
  const float* wv    = (const float*)d_in[4];
  const float* wo    = (const float*)d_in[5];
  const float* wob   = (const float*)d_in[6];
  const float* betas = (const float*)d_in[7];
  float* out = (float*)d_out;

  const size_t TOK = (size_t)M_TOK * D_DIM;  // 33.5M elements
  char* ws = (char*)d_ws;
  size_t off = 0;
  auto alloc = [&](size_t bytes) {
    char* p = ws + off;
    off += (bytes + 255) & ~(size_t)255;
    return p;
  };
  unsigned* wsp[4];
  for (int i = 0; i < 4; ++i)
    wsp[i] = (unsigned*)alloc((size_t)D_DIM * D_DIM * 4);  // 4 MiB each
  unsigned* qp = (unsigned*)alloc(TOK * 4);  // 128 MiB
  unsigned* kp = (unsigned*)alloc(TOK * 4);
  unsigned* vp = (unsigned*)alloc(TOK * 4);
  float* U   = (float*)alloc((size_t)B_DIM * NSEG * H_NUM * 4096 * 4);  // 16.8 MiB
  float* Mem = (float*)alloc((size_t)B_DIM * NSEG * H_NUM * 4096 * 4);
  float* Zs  = (float*)alloc((size_t)B_DIM * NSEG * H_NUM * 64 * 4);
  float* Zp  = (float*)alloc((size_t)B_DIM * NSEG * H_NUM * 64 * 4);
  // total ≈ 434 MiB < ws. att output written IN-PLACE over qp.

  if (off > ws_size) return;

  const float* wsrc[4] = {wq, wk, wv, wo};
  for (int i = 0; i < 4; ++i)
    split_pack<<<512, 256, 0, stream>>>(wsrc[i], wsp[i], D_DIM * D_DIM / 4);

  const int ggrid = (D_DIM / 128) * (M_TOK / 128);  // 2048, XCD-swizzled in-kernel
  gemm_bt<1><<<ggrid, 256, 0, stream>>>((const unsigned*)x, wsp[0], nullptr, nullptr,
                                        qp, M_TOK, D_DIM, D_DIM);
  gemm_bt<1><<<ggrid, 256, 0, stream>>>((const unsigned*)x, wsp[1], nullptr, nullptr,
                                        kp, M_TOK, D_DIM, D_DIM);
  gemm_bt<1><<<ggrid, 256, 0, stream>>>((const unsigned*)x, wsp[2], nullptr, nullptr,
                                        vp, M_TOK, D_DIM, D_DIM);

  seg_outer_mfma<<<B_DIM * NSEG * H_NUM, 256, 0, stream>>>(kp, vp, U, Zs);
  seg_prefix<<<dim3(B_DIM * H_NUM, 8), 256, 0, stream>>>(U, Zs, Mem, Zp);

  for (int b = 0; b < B_DIM; ++b)
    attn_seg_mfma<<<NSEG * H_NUM * 4, 512, 0, stream>>>(qp, kp, vp, mask, Mem, Zp,
                                                        betas, qp, b);

  gemm_bt<0><<<ggrid, 256, 0, stream>>>(qp, wsp[3], out, wob, nullptr,
                                        M_TOK, D_DIM, D_DIM);
}

// Round 11
// 961.285 us; speedup vs baseline: 1.5604x; 1.2779x over previous
//
#include <hip/hip_runtime.h>

typedef float fv2 __attribute__((ext_vector_type(2)));
typedef float fv4 __attribute__((ext_vector_type(4)));
typedef _Float16 hfv8 __attribute__((ext_vector_type(8)));
typedef unsigned short u16v4 __attribute__((ext_vector_type(4)));
typedef unsigned short u16v8 __attribute__((ext_vector_type(8)));
typedef unsigned int u32v2 __attribute__((ext_vector_type(2)));
typedef unsigned int u32v4 __attribute__((ext_vector_type(4)));

#define B_DIM 4
#define L_DIM 8192
#define D_DIM 1024
#define H_NUM 16
#define NSEG 16
#define SEG_S 512
#define M_TOK (B_DIM * L_DIM)  // 32768

__device__ __forceinline__ unsigned short f2h(float f) {
  return __builtin_bit_cast(unsigned short, (_Float16)f);  // v_cvt_f16_f32 RNE
}
__device__ __forceinline__ float h2f(unsigned short u) {
  return (float)__builtin_bit_cast(_Float16, u);
}
// packed fp16 pair: hi in low 16 bits, lo residual in high 16 bits
__device__ __forceinline__ unsigned packh2(float v) {
  const _Float16 h = (_Float16)v;
  const unsigned short lb = __builtin_bit_cast(unsigned short, (_Float16)(v - (float)h));
  return (unsigned)__builtin_bit_cast(unsigned short, h) | ((unsigned)lb << 16);
}

// barrier that drains ONLY LDS ops — leaves global prefetch in flight (T4).
__device__ __forceinline__ void barrier_lgkm() {
  asm volatile("s_waitcnt lgkmcnt(0)" ::: "memory");
  __builtin_amdgcn_s_barrier();
}

// unpack 8 packed pairs (2 x u32v4) -> u16v8 hi plane and u16v8 lo plane
__device__ __forceinline__ void unpack8(u32v4 a, u32v4 b, u16v8& hi8, u16v8& lo8) {
  u32v4 hi, lo;
  hi[0] = __builtin_amdgcn_perm(a[1], a[0], 0x05040100u);
  hi[1] = __builtin_amdgcn_perm(a[3], a[2], 0x05040100u);
  hi[2] = __builtin_amdgcn_perm(b[1], b[0], 0x05040100u);
  hi[3] = __builtin_amdgcn_perm(b[3], b[2], 0x05040100u);
  lo[0] = __builtin_amdgcn_perm(a[1], a[0], 0x07060302u);
  lo[1] = __builtin_amdgcn_perm(a[3], a[2], 0x07060302u);
  lo[2] = __builtin_amdgcn_perm(b[1], b[0], 0x07060302u);
  lo[3] = __builtin_amdgcn_perm(b[3], b[2], 0x07060302u);
  hi8 = __builtin_bit_cast(u16v8, hi);
  lo8 = __builtin_bit_cast(u16v8, lo);
}
// hi plane only (4 perms)
__device__ __forceinline__ u16v8 hi8of(u32v4 a, u32v4 b) {
  u32v4 hi;
  hi[0] = __builtin_amdgcn_perm(a[1], a[0], 0x05040100u);
  hi[1] = __builtin_amdgcn_perm(a[3], a[2], 0x05040100u);
  hi[2] = __builtin_amdgcn_perm(b[1], b[0], 0x05040100u);
  hi[3] = __builtin_amdgcn_perm(b[3], b[2], 0x05040100u);
  return __builtin_bit_cast(u16v8, hi);
}
// split 8 fp32 -> fp16 hi/lo planes
__device__ __forceinline__ void split8h(const unsigned* pr, u16v8& hi8, u16v8& lo8) {
#pragma unroll
  for (int j = 0; j < 8; ++j) {
    const float v = __uint_as_float(pr[j]);
    const _Float16 h = (_Float16)v;
    hi8[j] = __builtin_bit_cast(unsigned short, h);
    lo8[j] = __builtin_bit_cast(unsigned short, (_Float16)(v - (float)h));
  }
}

// ---------------- fp32 weights -> single fp16 plane ----------------
__global__ __launch_bounds__(256) void conv_w16(
    const float* __restrict__ in, unsigned short* __restrict__ outp, int n4) {
  int i = blockIdx.x * 256 + threadIdx.x;
  const int stride = gridDim.x * 256;
  for (; i < n4; i += stride) {
    fv4 v = reinterpret_cast<const fv4*>(in)[i];
    u16v4 p;
#pragma unroll
    for (int j = 0; j < 4; ++j) p[j] = f2h(v[j]);
    reinterpret_cast<u16v4*>(outp)[i] = p;
  }
}

// ---------------- C[M,N] = A @ B^T, fp16 2-product MFMA ----------------
// A: 2-plane fp16 (from fp32 if ASPLIT=1, packed u32 if ASPLIT=0). B: single fp16 plane.
// C = A_hi.B + A_lo.B  (residual A.B_res ~ 2.8e-4 relative).
#define GT_PAD 40
template <int ASPLIT>
__global__ __launch_bounds__(256, 3) void gemm_bt(
    const unsigned* __restrict__ Ap, const unsigned short* __restrict__ B16,
    float* __restrict__ C, const float* __restrict__ bias,
    unsigned* __restrict__ Cp, int M, int N, int K) {
  __shared__ _Float16 sAh[128 * GT_PAD], sAl[128 * GT_PAD];
  __shared__ _Float16 sB[128 * GT_PAD];
  const int tid = threadIdx.x;
  const int lane = tid & 63;
  const int wid = tid >> 6;
  const int wr = wid >> 1, wc = wid & 1;

  // T1 XCD swizzle: 8 N-tiles of one M-panel share one XCD (round-robin hw%8).
  const int hw = blockIdx.x;
  const int xcd = hw & 7;
  const int rem = hw >> 3;
  const int ntile = rem & 7;
  const int yhi = rem >> 3;
  const int mtile = yhi * 8 + xcd;
  const int mBase = mtile * 128;
  const int nBase = ntile * 128;

  fv4 acc[4][4] = {};

  const int arowRd = wr * 64 + (lane & 15);
  const int browRd = wc * 64 + (lane & 15);
  const int koff = (lane >> 4) << 3;

  const int srow0 = tid >> 2, srow1 = (256 + tid) >> 2, sch = tid & 3;
  const int ldo0 = srow0 * GT_PAD + sch * 8;
  const int ldo1 = srow1 * GT_PAD + sch * 8;

  u32v4 pa0[2], pa1[2];
  u16v8 pb0, pb1;
  auto LOADK = [&](int k0) {
    const long ga0 = (long)(mBase + srow0) * K + k0 + sch * 8;
    const long ga1 = (long)(mBase + srow1) * K + k0 + sch * 8;
    const long gb0 = (long)(nBase + srow0) * K + k0 + sch * 8;
    const long gb1 = (long)(nBase + srow1) * K + k0 + sch * 8;
    pa0[0] = *(const u32v4*)&Ap[ga0]; pa0[1] = *(const u32v4*)&Ap[ga0 + 4];
    pa1[0] = *(const u32v4*)&Ap[ga1]; pa1[1] = *(const u32v4*)&Ap[ga1 + 4];
    pb0 = *(const u16v8*)&B16[gb0];
    pb1 = *(const u16v8*)&B16[gb1];
  };
  LOADK(0);

  for (int k0 = 0; k0 < K; k0 += 32) {
    barrier_lgkm();  // prev frag reads retired; vmcnt NOT drained
    {
      u16v8 hi8, lo8;
      if (ASPLIT) split8h((const unsigned*)pa0, hi8, lo8);
      else unpack8(pa0[0], pa0[1], hi8, lo8);
      *(u16v8*)&sAh[ldo0] = hi8; *(u16v8*)&sAl[ldo0] = lo8;
      if (ASPLIT) split8h((const unsigned*)pa1, hi8, lo8);
      else unpack8(pa1[0], pa1[1], hi8, lo8);
      *(u16v8*)&sAh[ldo1] = hi8; *(u16v8*)&sAl[ldo1] = lo8;
      *(u16v8*)&sB[ldo0] = pb0;  // B: pure copy, no unpack
      *(u16v8*)&sB[ldo1] = pb1;
    }
    if (k0 + 32 < K) LOADK(k0 + 32);  // stays in flight across barrier (T14/T4)
    barrier_lgkm();
    hfv8 fah[4], fal[4], fb[4];
#pragma unroll
    for (int i = 0; i < 4; ++i) {
      fah[i] = *(const hfv8*)&sAh[(arowRd + i * 16) * GT_PAD + koff];
      fal[i] = *(const hfv8*)&sAl[(arowRd + i * 16) * GT_PAD + koff];
      fb[i]  = *(const hfv8*)&sB[(browRd + i * 16) * GT_PAD + koff];
    }
#pragma unroll
    for (int i = 0; i < 4; ++i)
#pragma unroll
      for (int j = 0; j < 4; ++j) {
        acc[i][j] = __builtin_amdgcn_mfma_f32_16x16x32_f16(fah[i], fb[j], acc[i][j], 0, 0, 0);
        acc[i][j] = __builtin_amdgcn_mfma_f32_16x16x32_f16(fal[i], fb[j], acc[i][j], 0, 0, 0);
      }
  }

  // C/D layout (m89, dtype-independent): col = lane&15, row = 4*(lane>>4) + reg
  const int crow0 = mBase + wr * 64 + ((lane >> 4) << 2);
  const int ccol0 = nBase + wc * 64 + (lane & 15);
  if (Cp) {
#pragma unroll
    for (int j = 0; j < 4; ++j) {
      const int col = ccol0 + j * 16;
#pragma unroll
      for (int i = 0; i < 4; ++i) {
        const long rb = (long)(crow0 + i * 16) * N + col;
#pragma unroll
        for (int r = 0; r < 4; ++r)
          Cp[rb + (long)r * N] = packh2(acc[i][j][r]);
      }
    }
  } else {
#pragma unroll
    for (int j = 0; j < 4; ++j) {
      const int col = ccol0 + j * 16;
      const float bv = bias ? bias[col] : 0.f;
#pragma unroll
      for (int i = 0; i < 4; ++i) {
        const long rb = (long)(crow0 + i * 16) * N + col;
#pragma unroll
        for (int r = 0; r < 4; ++r)
          C[rb + (long)r * N] = acc[i][j][r] + bv;
      }
    }
  }
}

// ---------------- per-(b,seg,h) outer products: U = akT.v, fp16 2-product ----------------
// ak 2-plane fp16 (exact-ish), v hi-plane fp16.
__global__ __launch_bounds__(256) void seg_outer_mfma(
    const unsigned* __restrict__ Kp, const unsigned* __restrict__ Vp,
    float* __restrict__ U, float* __restrict__ Zs) {
  __shared__ _Float16 sAh[64 * 64], sAl[64 * 64];  // akT [d][s]
  __shared__ _Float16 sVh[64 * 64];                // vT  [e][s]
  __shared__ float sZf[64];
  const int bid = blockIdx.x;  // b*256 + seg*16 + h
  const int b = bid >> 8, seg = (bid >> 4) & 15, h = bid & 15;
  const int tid = threadIdx.x;
  const int lane = tid & 63, w = tid >> 6;
  const int g = lane >> 4, ln16 = lane & 15;
  const long base = ((long)b * L_DIM + (long)seg * SEG_S) * D_DIM + h * 64;

  if (tid < 64) sZf[tid] = 0.f;
  fv4 acc[4] = {};
  float zacc = 0.f;
  const int strow = tid & 63;
  const int sg0 = (tid >> 6) * 16;
  const int wsw = (strow & 7) << 3;
  const int rsw = (ln16 & 7) << 3;

  for (int c = 0; c < 8; ++c) {
    __syncthreads();
#pragma unroll
    for (int jj = 0; jj < 2; ++jj) {
      u16v8 ah, al, vh;
#pragma unroll
      for (int i = 0; i < 8; ++i) {
        const long gidx = base + (long)(c * 64 + sg0 + jj * 8 + i) * D_DIM + strow;
        const unsigned ku = Kp[gidx];
        const unsigned vu = Vp[gidx];
        const float kv = h2f((unsigned short)(ku & 0xffffu)) +
                         h2f((unsigned short)(ku >> 16));
        const float a = kv > 0.f ? kv + 1.f : __expf(kv);
        zacc += a;
        const unsigned short hb = f2h(a);
        ah[i] = hb;
        al[i] = f2h(a - h2f(hb));
        vh[i] = (unsigned short)(vu & 0xffffu);
      }
      const int col = (sg0 + jj * 8) ^ wsw;
      *(u16v8*)&sAh[strow * 64 + col] = ah;
      *(u16v8*)&sAl[strow * 64 + col] = al;
      *(u16v8*)&sVh[strow * 64 + col] = vh;
    }
    __syncthreads();
#pragma unroll
    for (int kf = 0; kf < 2; ++kf) {
      const int so = (kf * 32 + g * 8) ^ rsw;
      hfv8 aH = *(const hfv8*)&sAh[(w * 16 + ln16) * 64 + so];
      hfv8 aL = *(const hfv8*)&sAl[(w * 16 + ln16) * 64 + so];
#pragma unroll
      for (int et = 0; et < 4; ++et) {
        hfv8 bH = *(const hfv8*)&sVh[(et * 16 + ln16) * 64 + so];
        acc[et] = __builtin_amdgcn_mfma_f32_16x16x32_f16(aH, bH, acc[et], 0, 0, 0);
        acc[et] = __builtin_amdgcn_mfma_f32_16x16x32_f16(aL, bH, acc[et], 0, 0, 0);
      }
    }
  }
  atomicAdd(&sZf[strow], zacc);
  __syncthreads();

  const long ub = (long)bid * 4096;
#pragma unroll
  for (int et = 0; et < 4; ++et)
#pragma unroll
    for (int r = 0; r < 4; ++r)
      U[ub + (long)(w * 16 + g * 4 + r) * 64 + et * 16 + ln16] = acc[et][r];
  if (tid < 64) Zs[(long)bid * 64 + tid] = sZf[tid];
}

// ---------------- exclusive prefix over segments (per b,h) ----------------
__global__ __launch_bounds__(256) void seg_prefix(
    const float* __restrict__ U, const float* __restrict__ Zs,
    float* __restrict__ Mem, float* __restrict__ Zp) {
  const int bh = blockIdx.x;
  const int b = bh >> 4, h = bh & 15;
  const int jc = blockIdx.y;
  const int tid = threadIdx.x;
  for (int j = jc * 512 + tid; j < jc * 512 + 512; j += 256) {
    float run = 0.f;
#pragma unroll
    for (int t = 0; t < NSEG; ++t) {
      const long idx = ((long)(b * 256 + t * 16 + h)) * 4096 + j;
      Mem[idx] = run;
      run += U[idx];
    }
  }
  if (jc == 0 && tid < 64) {
    float run = 0.f;
#pragma unroll
    for (int t = 0; t < NSEG; ++t) {
      const long idx = ((long)(b * 256 + t * 16 + h)) * 64 + tid;
      Zp[idx] = run;
      run += Zs[idx];
    }
  }
}

// ---------------- MFMA segment attention, fp16: per-batch, in-place att over Q ----------------
// QK = K_hi.(Q_hi+Q_lo); Mem-term = Mem_hi.(aq_hi+aq_lo); V,P fp16 single.
__global__ __launch_bounds__(512, 4) void attn_seg_mfma(
    const unsigned* Qp, const unsigned* __restrict__ Kp,
    const unsigned* __restrict__ Vp, const int* __restrict__ mask,
    const float* __restrict__ Mem, const float* __restrict__ Zp,
    const float* __restrict__ betas, unsigned* Op, int b) {
  __shared__ _Float16 sKh[64 * 72];   // K chunk [key][d] hi; later Mem^T [e][d] hi
  __shared__ _Float16 sVTh[64 * 64];  // V^T [e][key], swizzled, hi
  __shared__ _Float16 sP[8][16 * 72]; // per-wave P fp16 [q][key]
  __shared__ float sMadd[64], sZ[64], sGate[64];

  const int bx = (blockIdx.x & 7) * 128 + (blockIdx.x >> 3);  // T1 bijective
  const int qblk = bx & 3, h = (bx >> 2) & 15, seg = bx >> 6;
  const int shb = b * 256 + seg * 16 + h;
  const int tid = threadIdx.x;
  const int lane = tid & 63, w = tid >> 6;
  const int g = lane >> 4, ln16 = lane & 15;
  const int rsw = (ln16 & 7) << 3;

  const int qglob = b * L_DIM + seg * SEG_S + qblk * 128 + w * 16 + ln16;
  const long qbase = (long)qglob * D_DIM + h * 64;
  hfv8 qh[2], ql[2];
#pragma unroll
  for (int dt = 0; dt < 2; ++dt) {
    u32v4 a = *(const u32v4*)&Qp[qbase + dt * 32 + g * 8];
    u32v4 bb = *(const u32v4*)&Qp[qbase + dt * 32 + g * 8 + 4];
    u16v8 hi8, lo8;
    unpack8(a, bb, hi8, lo8);
    qh[dt] = __builtin_bit_cast(hfv8, hi8);
    ql[dt] = __builtin_bit_cast(hfv8, lo8);
  }

  fv4 O[4] = {};
  float m_run = -1e30f, l_run = 0.f;
  const long kvbase0 = ((long)b * L_DIM + (long)seg * SEG_S) * D_DIM + h * 64;

  for (int c = 0; c < 8; ++c) {
    __syncthreads();
    {  // stage K hi [64 key][64 d]
      const int row = tid >> 3, d0 = (tid & 7) * 8;
      const long ga = kvbase0 + (long)(c * 64 + row) * D_DIM + d0;
      u32v4 a = *(const u32v4*)&Kp[ga], bb = *(const u32v4*)&Kp[ga + 4];
      *(u16v8*)&sKh[row * 72 + d0] = hi8of(a, bb);
    }
    {  // stage V^T hi [64 e][64 key], XOR-swizzled
      const int e = tid & 63, kg = (tid >> 6) * 8;
      u16v8 hv;
#pragma unroll
      for (int j = 0; j < 8; ++j) {
        const unsigned u = Vp[kvbase0 + (long)(c * 64 + kg + j) * D_DIM + e];
        hv[j] = (unsigned short)(u & 0xffffu);
      }
      *(u16v8*)&sVTh[e * 64 + (kg ^ ((e & 7) << 3))] = hv;
    }
    if (tid < 64)
      sMadd[tid] = (mask[b * L_DIM + seg * SEG_S + c * 64 + tid] == 0) ? -1e9f : 0.f;
    __syncthreads();

    fv4 madd[4];
#pragma unroll
    for (int kt = 0; kt < 4; ++kt) madd[kt] = *(const fv4*)&sMadd[kt * 16 + g * 4];

    // S^T = K_hi . (Q_hi + Q_lo)
    fv4 sc[4];
#pragma unroll
    for (int kt = 0; kt < 4; ++kt) {
      const int ro = (kt * 16 + ln16) * 72 + g * 8;
      hfv8 kh0 = *(const hfv8*)&sKh[ro], kh1 = *(const hfv8*)&sKh[ro + 32];
      fv4 s = {};
      s = __builtin_amdgcn_mfma_f32_16x16x32_f16(kh0, qh[0], s, 0, 0, 0);
      s = __builtin_amdgcn_mfma_f32_16x16x32_f16(kh1, qh[1], s, 0, 0, 0);
      s = __builtin_amdgcn_mfma_f32_16x16x32_f16(kh0, ql[0], s, 0, 0, 0);
      s = __builtin_amdgcn_mfma_f32_16x16x32_f16(kh1, ql[1], s, 0, 0, 0);
      sc[kt] = s;
    }
    // online softmax (defer-max THR=8)
    float pmax = -3.0e38f;
#pragma unroll
    for (int kt = 0; kt < 4; ++kt)
#pragma unroll
      for (int r = 0; r < 4; ++r) {
        const float v = __builtin_fmaf(sc[kt][r], 0.125f, madd[kt][r]);
        sc[kt][r] = v;
        pmax = fmaxf(pmax, v);
      }
    pmax = fmaxf(pmax, __shfl_xor(pmax, 16));
    pmax = fmaxf(pmax, __shfl_xor(pmax, 32));
    if (pmax > m_run + 8.f) {
      const float resc = __expf(m_run - pmax);
      l_run *= resc;
#pragma unroll
      for (int et = 0; et < 4; ++et)
#pragma unroll
        for (int r = 0; r < 4; ++r) O[et][r] *= resc;
      m_run = pmax;
    }
    float psum = 0.f;
#pragma unroll
    for (int kt = 0; kt < 4; ++kt) {
      u16v4 pv;
#pragma unroll
      for (int r = 0; r < 4; ++r) {
        const unsigned short hb = f2h(__expf(sc[kt][r] - m_run));
        pv[r] = hb;
        psum += h2f(hb);
      }
      *(u16v4*)&sP[w][ln16 * 72 + kt * 16 + g * 4] = pv;
    }
    psum += __shfl_xor(psum, 16);
    psum += __shfl_xor(psum, 32);
    l_run += psum;

    hfv8 pf0 = *(const hfv8*)&sP[w][ln16 * 72 + g * 8];
    hfv8 pf1 = *(const hfv8*)&sP[w][ln16 * 72 + 32 + g * 8];
    // O^T += V^T . P
#pragma unroll
    for (int et = 0; et < 4; ++et) {
      const int rb = (et * 16 + ln16) * 64;
      hfv8 vh0 = *(const hfv8*)&sVTh[rb + ((g * 8) ^ rsw)];
      hfv8 vh1 = *(const hfv8*)&sVTh[rb + ((g * 8 + 32) ^ rsw)];
      fv4 o = O[et];
      o = __builtin_amdgcn_mfma_f32_16x16x32_f16(vh0, pf0, o, 0, 0, 0);
      o = __builtin_amdgcn_mfma_f32_16x16x32_f16(vh1, pf1, o, 0, 0, 0);
      O[et] = o;
    }
  }

  // ---- memory-read term ----
  __syncthreads();
  {  // stage Mem^T hi [e][d] into sKh
    const int e2 = (tid & 31) * 2, d4 = (tid >> 5) * 4;
    const float* Memp = Mem + (long)shb * 4096;
    fv2 ld[4];
#pragma unroll
    for (int i = 0; i < 4; ++i) ld[i] = *(const fv2*)&Memp[(d4 + i) * 64 + e2];
#pragma unroll
    for (int je = 0; je < 2; ++je) {
      u16v4 hv;
#pragma unroll
      for (int i = 0; i < 4; ++i) hv[i] = f2h(ld[i][je]);
      *(u16v4*)&sKh[(e2 + je) * 72 + d4] = hv;
    }
  }
  if (tid < 64) {
    sZ[tid] = Zp[(long)shb * 64 + tid];
    sGate[tid] = 1.f / (1.f + __expf(-betas[h * 64 + tid]));
  }
  __syncthreads();

  // aq = elu(q)+1 split fp16; denom = aq . z (fp32)
  float dpart = 0.f;
#pragma unroll
  for (int dt = 0; dt < 2; ++dt) {
    u16v8 ah, al;
#pragma unroll
    for (int j = 0; j < 8; ++j) {
      const float x = (float)qh[dt][j] + (float)ql[dt][j];
      const float a = x > 0.f ? x + 1.f : __expf(x);
      dpart += a * sZ[dt * 32 + g * 8 + j];
      const unsigned short hb = f2h(a);
      ah[j] = hb;
      al[j] = f2h(a - h2f(hb));
    }
    qh[dt] = __builtin_bit_cast(hfv8, ah);
    ql[dt] = __builtin_bit_cast(hfv8, al);
  }
  dpart += __shfl_xor(dpart, 16);
  dpart += __shfl_xor(dpart, 32);
  const float invden = 1.f / (dpart + 1e-9f);
  const float invl = 1.f / l_run;

  const long obase = (long)qglob * D_DIM + h * 64;
#pragma unroll
  for (int et = 0; et < 4; ++et) {
    const int ro = (et * 16 + ln16) * 72 + g * 8;
    hfv8 mh0 = *(const hfv8*)&sKh[ro], mh1 = *(const hfv8*)&sKh[ro + 32];
    fv4 o = {};
    o = __builtin_amdgcn_mfma_f32_16x16x32_f16(mh0, qh[0], o, 0, 0, 0);
    o = __builtin_amdgcn_mfma_f32_16x16x32_f16(mh1, qh[1], o, 0, 0, 0);
    o = __builtin_amdgcn_mfma_f32_16x16x32_f16(mh0, ql[0], o, 0, 0, 0);
    o = __builtin_amdgcn_mfma_f32_16x16x32_f16(mh1, ql[1], o, 0, 0, 0);
    const fv4 gt = *(const fv4*)&sGate[et * 16 + g * 4];
    u32v4 st;
#pragma unroll
    for (int r = 0; r < 4; ++r) {
      const float att = gt[r] * o[r] * invden + (1.f - gt[r]) * O[et][r] * invl;
      st[r] = packh2(att);
    }
    *(u32v4*)&Op[obase + et * 16 + g * 4] = st;
  }
}

// ---------------- host launch ----------------
extern "C" void kernel_launch(void* const* d_in, const int* in_sizes, int n_in,
                              void* d_out, int out_size, void* d_ws, size_t ws_size,
                              hipStream_t stream) {
  (void)in_sizes; (void)n_in; (void)out_size;
  const float* x     = (const float*)d_in[0];
  const int*   mask  = (const int*)d_in[1];
  const float* wq    = (const float*)d_in[2];
  const float* wk    = (const float*)d_in[3];
  const float* wv    = (const float*)d_in[4];
  const float* wo    = (const float*)d_in[5];
  const float* wob   = (const float*)d_in[6];
  const float* betas = (const float*)d_in[7];
  float* out = (float*)d_out;

  const size_t TOK = (size_t)M_TOK * D_DIM;
  char* ws = (char*)d_ws;
  size_t off = 0;
  auto alloc = [&](size_t bytes) {
    char* p = ws + off;
    off += (bytes + 255) & ~(size_t)255;
    return p;
  };
  unsigned short* w16[4];
  for (int i = 0; i < 4; ++i)
    w16[i] = (unsigned short*)alloc((size_t)D_DIM * D_DIM * 2);  // 2 MiB each
  unsigned* qp = (unsigned*)alloc(TOK * 4);  // 128 MiB
  unsigned* kp = (unsigned*)alloc(TOK * 4);
  unsigned* vp = (unsigned*)alloc(TOK * 4);
  float* U   = (float*)alloc((size_t)B_DIM * NSEG * H_NUM * 4096 * 4);
  float* Mem = (float*)alloc((size_t)B_DIM * NSEG * H_NUM * 4096 * 4);
  float* Zs  = (float*)alloc((size_t)B_DIM * NSEG * H_NUM * 64 * 4);
  float* Zp  = (float*)alloc((size_t)B_DIM * NSEG * H_NUM * 64 * 4);
  // att output written IN-PLACE over qp.

  if (off > ws_size) return;

  const float* wsrc[4] = {wq, wk, wv, wo};
  for (int i = 0; i < 4; ++i)
    conv_w16<<<256, 256, 0, stream>>>(wsrc[i], w16[i], D_DIM * D_DIM / 4);

  const int ggrid = (D_DIM / 128) * (M_TOK / 128);  // 2048, XCD-swizzled
  gemm_bt<1><<<ggrid, 256, 0, stream>>>((const unsigned*)x, w16[0], nullptr, nullptr,
                                        qp, M_TOK, D_DIM, D_DIM);
  gemm_bt<1><<<ggrid, 256, 0, stream>>>((const unsigned*)x, w16[1], nullptr, nullptr,
                                        kp, M_TOK, D_DIM, D_DIM);
  gemm_bt<1><<<ggrid, 256, 0, stream>>>((const unsigned*)x, w16[2], nullptr, nullptr,
                                        vp, M_TOK, D_DIM, D_DIM);

  seg_outer_mfma<<<B_DIM * NSEG * H_NUM, 256, 0, stream>>>(kp, vp, U, Zs);
  seg_prefix<<<dim3(B_DIM * H_NUM, 8), 256, 0, stream>>>(U, Zs, Mem, Zp);

  for (int b = 0; b < B_DIM; ++b)
    attn_seg_mfma<<<NSEG * H_NUM * 4, 512, 0, stream>>>(qp, kp, vp, mask, Mem, Zp,
                                                        betas, qp, b);

  gemm_bt<0><<<ggrid, 256, 0, stream>>>(qp, w16[3], out, wob, nullptr,
                                        M_TOK, D_DIM, D_DIM);
}

// Round 12
// 849.140 us; speedup vs baseline: 1.7664x; 1.1321x over previous
//
#include <hip/hip_runtime.h>

typedef float fv2 __attribute__((ext_vector_type(2)));
typedef float fv4 __attribute__((ext_vector_type(4)));
typedef _Float16 hfv8 __attribute__((ext_vector_type(8)));
typedef unsigned short u16v4 __attribute__((ext_vector_type(4)));
typedef unsigned short u16v8 __attribute__((ext_vector_type(8)));
typedef unsigned int u32v2 __attribute__((ext_vector_type(2)));
typedef unsigned int u32v4 __attribute__((ext_vector_type(4)));

#define B_DIM 4
#define L_DIM 8192
#define D_DIM 1024
#define H_NUM 16
#define NSEG 16
#define SEG_S 512
#define M_TOK (B_DIM * L_DIM)  // 32768

__device__ __forceinline__ unsigned short f2h(float f) {
  return __builtin_bit_cast(unsigned short, (_Float16)f);  // v_cvt_f16_f32 RNE
}
__device__ __forceinline__ float h2f(unsigned short u) {
  return (float)__builtin_bit_cast(_Float16, u);
}
// packed fp16 pair: hi in low 16 bits, lo residual in high 16 bits
__device__ __forceinline__ unsigned packh2(float v) {
  const _Float16 h = (_Float16)v;
  const unsigned short lb = __builtin_bit_cast(unsigned short, (_Float16)(v - (float)h));
  return (unsigned)__builtin_bit_cast(unsigned short, h) | ((unsigned)lb << 16);
}

// barrier that drains ONLY LDS ops — leaves global prefetch in flight (T4).
__device__ __forceinline__ void barrier_lgkm() {
  asm volatile("s_waitcnt lgkmcnt(0)" ::: "memory");
  __builtin_amdgcn_s_barrier();
}

// unpack 8 packed pairs (2 x u32v4) -> u16v8 hi plane and u16v8 lo plane
__device__ __forceinline__ void unpack8(u32v4 a, u32v4 b, u16v8& hi8, u16v8& lo8) {
  u32v4 hi, lo;
  hi[0] = __builtin_amdgcn_perm(a[1], a[0], 0x05040100u);
  hi[1] = __builtin_amdgcn_perm(a[3], a[2], 0x05040100u);
  hi[2] = __builtin_amdgcn_perm(b[1], b[0], 0x05040100u);
  hi[3] = __builtin_amdgcn_perm(b[3], b[2], 0x05040100u);
  lo[0] = __builtin_amdgcn_perm(a[1], a[0], 0x07060302u);
  lo[1] = __builtin_amdgcn_perm(a[3], a[2], 0x07060302u);
  lo[2] = __builtin_amdgcn_perm(b[1], b[0], 0x07060302u);
  lo[3] = __builtin_amdgcn_perm(b[3], b[2], 0x07060302u);
  hi8 = __builtin_bit_cast(u16v8, hi);
  lo8 = __builtin_bit_cast(u16v8, lo);
}
// hi plane only (4 perms)
__device__ __forceinline__ u16v8 hi8of(u32v4 a, u32v4 b) {
  u32v4 hi;
  hi[0] = __builtin_amdgcn_perm(a[1], a[0], 0x05040100u);
  hi[1] = __builtin_amdgcn_perm(a[3], a[2], 0x05040100u);
  hi[2] = __builtin_amdgcn_perm(b[1], b[0], 0x05040100u);
  hi[3] = __builtin_amdgcn_perm(b[3], b[2], 0x05040100u);
  return __builtin_bit_cast(u16v8, hi);
}
// convert 8 fp32 (raw u32) -> fp16 single plane
__device__ __forceinline__ u16v8 cvt8h(const unsigned* pr) {
  u16v8 o;
#pragma unroll
  for (int j = 0; j < 8; ++j) o[j] = f2h(__uint_as_float(pr[j]));
  return o;
}

// ---------------- fp32 weights -> single fp16 plane ----------------
__global__ __launch_bounds__(256) void conv_w16(
    const float* __restrict__ in, unsigned short* __restrict__ outp, int n4) {
  int i = blockIdx.x * 256 + threadIdx.x;
  const int stride = gridDim.x * 256;
  for (; i < n4; i += stride) {
    fv4 v = reinterpret_cast<const fv4*>(in)[i];
    u16v4 p;
#pragma unroll
    for (int j = 0; j < 4; ++j) p[j] = f2h(v[j]);
    reinterpret_cast<u16v4*>(outp)[i] = p;
  }
}

// ---------------- C[M,N] = A @ B^T, pure fp16 single-plane MFMA ----------------
// A: fp32 (ASPLIT=1) or packed fp16-pair u32 (ASPLIT=0), staged as ONE fp16 plane.
// B: single fp16 plane. C = A_hi . B  (rounding ~2.8e-4 rel — measured invisible
// at output: rounds 6-10 tolerated 2.3e-3-rel V rounding with absmax unchanged).
#define GT_PAD 40
template <int ASPLIT>
__global__ __launch_bounds__(256, 4) void gemm_bt(
    const unsigned* __restrict__ Ap, const unsigned short* __restrict__ B16,
    float* __restrict__ C, const float* __restrict__ bias,
    unsigned* __restrict__ Cp, int M, int N, int K) {
  __shared__ _Float16 sA[128 * GT_PAD];
  __shared__ _Float16 sB[128 * GT_PAD];
  const int tid = threadIdx.x;
  const int lane = tid & 63;
  const int wid = tid >> 6;
  const int wr = wid >> 1, wc = wid & 1;

  // T1 XCD swizzle: 8 N-tiles of one M-panel share one XCD (round-robin hw%8).
  const int hw = blockIdx.x;
  const int xcd = hw & 7;
  const int rem = hw >> 3;
  const int ntile = rem & 7;
  const int yhi = rem >> 3;
  const int mtile = yhi * 8 + xcd;
  const int mBase = mtile * 128;
  const int nBase = ntile * 128;

  fv4 acc[4][4] = {};

  const int arowRd = wr * 64 + (lane & 15);
  const int browRd = wc * 64 + (lane & 15);
  const int koff = (lane >> 4) << 3;

  const int srow0 = tid >> 2, srow1 = (256 + tid) >> 2, sch = tid & 3;
  const int ldo0 = srow0 * GT_PAD + sch * 8;
  const int ldo1 = srow1 * GT_PAD + sch * 8;

  u32v4 pa0[2], pa1[2];
  u16v8 pb0, pb1;
  auto LOADK = [&](int k0) {
    const long ga0 = (long)(mBase + srow0) * K + k0 + sch * 8;
    const long ga1 = (long)(mBase + srow1) * K + k0 + sch * 8;
    const long gb0 = (long)(nBase + srow0) * K + k0 + sch * 8;
    const long gb1 = (long)(nBase + srow1) * K + k0 + sch * 8;
    pa0[0] = *(const u32v4*)&Ap[ga0]; pa0[1] = *(const u32v4*)&Ap[ga0 + 4];
    pa1[0] = *(const u32v4*)&Ap[ga1]; pa1[1] = *(const u32v4*)&Ap[ga1 + 4];
    pb0 = *(const u16v8*)&B16[gb0];
    pb1 = *(const u16v8*)&B16[gb1];
  };
  LOADK(0);

  for (int k0 = 0; k0 < K; k0 += 32) {
    barrier_lgkm();  // prev frag reads retired; vmcnt NOT drained
    {
      u16v8 a0 = ASPLIT ? cvt8h((const unsigned*)pa0) : hi8of(pa0[0], pa0[1]);
      u16v8 a1 = ASPLIT ? cvt8h((const unsigned*)pa1) : hi8of(pa1[0], pa1[1]);
      *(u16v8*)&sA[ldo0] = a0;
      *(u16v8*)&sA[ldo1] = a1;
      *(u16v8*)&sB[ldo0] = pb0;  // B: pure copy
      *(u16v8*)&sB[ldo1] = pb1;
    }
    if (k0 + 32 < K) LOADK(k0 + 32);  // stays in flight across barrier (T14/T4)
    barrier_lgkm();
    hfv8 fa[4], fb[4];
#pragma unroll
    for (int i = 0; i < 4; ++i) {
      fa[i] = *(const hfv8*)&sA[(arowRd + i * 16) * GT_PAD + koff];
      fb[i] = *(const hfv8*)&sB[(browRd + i * 16) * GT_PAD + koff];
    }
#pragma unroll
    for (int i = 0; i < 4; ++i)
#pragma unroll
      for (int j = 0; j < 4; ++j)
        acc[i][j] = __builtin_amdgcn_mfma_f32_16x16x32_f16(fa[i], fb[j], acc[i][j], 0, 0, 0);
  }

  // C/D layout (m89, dtype-independent): col = lane&15, row = 4*(lane>>4) + reg
  const int crow0 = mBase + wr * 64 + ((lane >> 4) << 2);
  const int ccol0 = nBase + wc * 64 + (lane & 15);
  if (Cp) {
#pragma unroll
    for (int j = 0; j < 4; ++j) {
      const int col = ccol0 + j * 16;
#pragma unroll
      for (int i = 0; i < 4; ++i) {
        const long rb = (long)(crow0 + i * 16) * N + col;
#pragma unroll
        for (int r = 0; r < 4; ++r)
          Cp[rb + (long)r * N] = packh2(acc[i][j][r]);
      }
    }
  } else {
#pragma unroll
    for (int j = 0; j < 4; ++j) {
      const int col = ccol0 + j * 16;
      const float bv = bias ? bias[col] : 0.f;
#pragma unroll
      for (int i = 0; i < 4; ++i) {
        const long rb = (long)(crow0 + i * 16) * N + col;
#pragma unroll
        for (int r = 0; r < 4; ++r)
          C[rb + (long)r * N] = acc[i][j][r] + bv;
      }
    }
  }
}

// ---------------- per-(b,seg,h) outer products: U = akT.v, fp16 2-product ----------------
// ak 2-plane fp16 (exact-ish), v hi-plane fp16.
__global__ __launch_bounds__(256) void seg_outer_mfma(
    const unsigned* __restrict__ Kp, const unsigned* __restrict__ Vp,
    float* __restrict__ U, float* __restrict__ Zs) {
  __shared__ _Float16 sAh[64 * 64], sAl[64 * 64];  // akT [d][s]
  __shared__ _Float16 sVh[64 * 64];                // vT  [e][s]
  __shared__ float sZf[64];
  const int bid = blockIdx.x;  // b*256 + seg*16 + h
  const int b = bid >> 8, seg = (bid >> 4) & 15, h = bid & 15;
  const int tid = threadIdx.x;
  const int lane = tid & 63, w = tid >> 6;
  const int g = lane >> 4, ln16 = lane & 15;
  const long base = ((long)b * L_DIM + (long)seg * SEG_S) * D_DIM + h * 64;

  if (tid < 64) sZf[tid] = 0.f;
  fv4 acc[4] = {};
  float zacc = 0.f;
  const int strow = tid & 63;
  const int sg0 = (tid >> 6) * 16;
  const int wsw = (strow & 7) << 3;
  const int rsw = (ln16 & 7) << 3;

  for (int c = 0; c < 8; ++c) {
    __syncthreads();
#pragma unroll
    for (int jj = 0; jj < 2; ++jj) {
      u16v8 ah, al, vh;
#pragma unroll
      for (int i = 0; i < 8; ++i) {
        const long gidx = base + (long)(c * 64 + sg0 + jj * 8 + i) * D_DIM + strow;
        const unsigned ku = Kp[gidx];
        const unsigned vu = Vp[gidx];
        const float kv = h2f((unsigned short)(ku & 0xffffu)) +
                         h2f((unsigned short)(ku >> 16));
        const float a = kv > 0.f ? kv + 1.f : __expf(kv);
        zacc += a;
        const unsigned short hb = f2h(a);
        ah[i] = hb;
        al[i] = f2h(a - h2f(hb));
        vh[i] = (unsigned short)(vu & 0xffffu);
      }
      const int col = (sg0 + jj * 8) ^ wsw;
      *(u16v8*)&sAh[strow * 64 + col] = ah;
      *(u16v8*)&sAl[strow * 64 + col] = al;
      *(u16v8*)&sVh[strow * 64 + col] = vh;
    }
    __syncthreads();
#pragma unroll
    for (int kf = 0; kf < 2; ++kf) {
      const int so = (kf * 32 + g * 8) ^ rsw;
      hfv8 aH = *(const hfv8*)&sAh[(w * 16 + ln16) * 64 + so];
      hfv8 aL = *(const hfv8*)&sAl[(w * 16 + ln16) * 64 + so];
#pragma unroll
      for (int et = 0; et < 4; ++et) {
        hfv8 bH = *(const hfv8*)&sVh[(et * 16 + ln16) * 64 + so];
        acc[et] = __builtin_amdgcn_mfma_f32_16x16x32_f16(aH, bH, acc[et], 0, 0, 0);
        acc[et] = __builtin_amdgcn_mfma_f32_16x16x32_f16(aL, bH, acc[et], 0, 0, 0);
      }
    }
  }
  atomicAdd(&sZf[strow], zacc);
  __syncthreads();

  const long ub = (long)bid * 4096;
#pragma unroll
  for (int et = 0; et < 4; ++et)
#pragma unroll
    for (int r = 0; r < 4; ++r)
      U[ub + (long)(w * 16 + g * 4 + r) * 64 + et * 16 + ln16] = acc[et][r];
  if (tid < 64) Zs[(long)bid * 64 + tid] = sZf[tid];
}

// ---------------- exclusive prefix over segments (per b,h) ----------------
__global__ __launch_bounds__(256) void seg_prefix(
    const float* __restrict__ U, const float* __restrict__ Zs,
    float* __restrict__ Mem, float* __restrict__ Zp) {
  const int bh = blockIdx.x;
  const int b = bh >> 4, h = bh & 15;
  const int jc = blockIdx.y;
  const int tid = threadIdx.x;
  for (int j = jc * 512 + tid; j < jc * 512 + 512; j += 256) {
    float run = 0.f;
#pragma unroll
    for (int t = 0; t < NSEG; ++t) {
      const long idx = ((long)(b * 256 + t * 16 + h)) * 4096 + j;
      Mem[idx] = run;
      run += U[idx];
    }
  }
  if (jc == 0 && tid < 64) {
    float run = 0.f;
#pragma unroll
    for (int t = 0; t < NSEG; ++t) {
      const long idx = ((long)(b * 256 + t * 16 + h)) * 64 + tid;
      Zp[idx] = run;
      run += Zs[idx];
    }
  }
}

// ---------------- MFMA segment attention, fp16: per-batch, in-place att over Q ----------------
__global__ __launch_bounds__(512, 4) void attn_seg_mfma(
    const unsigned* Qp, const unsigned* __restrict__ Kp,
    const unsigned* __restrict__ Vp, const int* __restrict__ mask,
    const float* __restrict__ Mem, const float* __restrict__ Zp,
    const float* __restrict__ betas, unsigned* Op, int b) {
  __shared__ _Float16 sKh[64 * 72];   // K chunk [key][d] hi; later Mem^T [e][d] hi
  __shared__ _Float16 sVTh[64 * 64];  // V^T [e][key], swizzled, hi
  __shared__ _Float16 sP[8][16 * 72]; // per-wave P fp16 [q][key]
  __shared__ float sMadd[64], sZ[64], sGate[64];

  const int bx = (blockIdx.x & 7) * 128 + (blockIdx.x >> 3);  // T1 bijective
  const int qblk = bx & 3, h = (bx >> 2) & 15, seg = bx >> 6;
  const int shb = b * 256 + seg * 16 + h;
  const int tid = threadIdx.x;
  const int lane = tid & 63, w = tid >> 6;
  const int g = lane >> 4, ln16 = lane & 15;
  const int rsw = (ln16 & 7) << 3;

  const int qglob = b * L_DIM + seg * SEG_S + qblk * 128 + w * 16 + ln16;
  const long qbase = (long)qglob * D_DIM + h * 64;
  hfv8 qh[2], ql[2];
#pragma unroll
  for (int dt = 0; dt < 2; ++dt) {
    u32v4 a = *(const u32v4*)&Qp[qbase + dt * 32 + g * 8];
    u32v4 bb = *(const u32v4*)&Qp[qbase + dt * 32 + g * 8 + 4];
    u16v8 hi8, lo8;
    unpack8(a, bb, hi8, lo8);
    qh[dt] = __builtin_bit_cast(hfv8, hi8);
    ql[dt] = __builtin_bit_cast(hfv8, lo8);
  }

  fv4 O[4] = {};
  float m_run = -1e30f, l_run = 0.f;
  const long kvbase0 = ((long)b * L_DIM + (long)seg * SEG_S) * D_DIM + h * 64;

  for (int c = 0; c < 8; ++c) {
    __syncthreads();
    {  // stage K hi [64 key][64 d]
      const int row = tid >> 3, d0 = (tid & 7) * 8;
      const long ga = kvbase0 + (long)(c * 64 + row) * D_DIM + d0;
      u32v4 a = *(const u32v4*)&Kp[ga], bb = *(const u32v4*)&Kp[ga + 4];
      *(u16v8*)&sKh[row * 72 + d0] = hi8of(a, bb);
    }
    {  // stage V^T hi [64 e][64 key], XOR-swizzled
      const int e = tid & 63, kg = (tid >> 6) * 8;
      u16v8 hv;
#pragma unroll
      for (int j = 0; j < 8; ++j) {
        const unsigned u = Vp[kvbase0 + (long)(c * 64 + kg + j) * D_DIM + e];
        hv[j] = (unsigned short)(u & 0xffffu);
      }
      *(u16v8*)&sVTh[e * 64 + (kg ^ ((e & 7) << 3))] = hv;
    }
    if (tid < 64)
      sMadd[tid] = (mask[b * L_DIM + seg * SEG_S + c * 64 + tid] == 0) ? -1e9f : 0.f;
    __syncthreads();

    fv4 madd[4];
#pragma unroll
    for (int kt = 0; kt < 4; ++kt) madd[kt] = *(const fv4*)&sMadd[kt * 16 + g * 4];

    // S^T = K_hi . (Q_hi + Q_lo)
    fv4 sc[4];
#pragma unroll
    for (int kt = 0; kt < 4; ++kt) {
      const int ro = (kt * 16 + ln16) * 72 + g * 8;
      hfv8 kh0 = *(const hfv8*)&sKh[ro], kh1 = *(const hfv8*)&sKh[ro + 32];
      fv4 s = {};
      s = __builtin_amdgcn_mfma_f32_16x16x32_f16(kh0, qh[0], s, 0, 0, 0);
      s = __builtin_amdgcn_mfma_f32_16x16x32_f16(kh1, qh[1], s, 0, 0, 0);
      s = __builtin_amdgcn_mfma_f32_16x16x32_f16(kh0, ql[0], s, 0, 0, 0);
      s = __builtin_amdgcn_mfma_f32_16x16x32_f16(kh1, ql[1], s, 0, 0, 0);
      sc[kt] = s;
    }
    // online softmax (defer-max THR=8)
    float pmax = -3.0e38f;
#pragma unroll
    for (int kt = 0; kt < 4; ++kt)
#pragma unroll
      for (int r = 0; r < 4; ++r) {
        const float v = __builtin_fmaf(sc[kt][r], 0.125f, madd[kt][r]);
        sc[kt][r] = v;
        pmax = fmaxf(pmax, v);
      }
    pmax = fmaxf(pmax, __shfl_xor(pmax, 16));
    pmax = fmaxf(pmax, __shfl_xor(pmax, 32));
    if (pmax > m_run + 8.f) {
      const float resc = __expf(m_run - pmax);
      l_run *= resc;
#pragma unroll
      for (int et = 0; et < 4; ++et)
#pragma unroll
        for (int r = 0; r < 4; ++r) O[et][r] *= resc;
      m_run = pmax;
    }
    float psum = 0.f;
#pragma unroll
    for (int kt = 0; kt < 4; ++kt) {
      u16v4 pv;
#pragma unroll
      for (int r = 0; r < 4; ++r) {
        const unsigned short hb = f2h(__expf(sc[kt][r] - m_run));
        pv[r] = hb;
        psum += h2f(hb);
      }
      *(u16v4*)&sP[w][ln16 * 72 + kt * 16 + g * 4] = pv;
    }
    psum += __shfl_xor(psum, 16);
    psum += __shfl_xor(psum, 32);
    l_run += psum;

    hfv8 pf0 = *(const hfv8*)&sP[w][ln16 * 72 + g * 8];
    hfv8 pf1 = *(const hfv8*)&sP[w][ln16 * 72 + 32 + g * 8];
    // O^T += V^T . P
#pragma unroll
    for (int et = 0; et < 4; ++et) {
      const int rb = (et * 16 + ln16) * 64;
      hfv8 vh0 = *(const hfv8*)&sVTh[rb + ((g * 8) ^ rsw)];
      hfv8 vh1 = *(const hfv8*)&sVTh[rb + ((g * 8 + 32) ^ rsw)];
      fv4 o = O[et];
      o = __builtin_amdgcn_mfma_f32_16x16x32_f16(vh0, pf0, o, 0, 0, 0);
      o = __builtin_amdgcn_mfma_f32_16x16x32_f16(vh1, pf1, o, 0, 0, 0);
      O[et] = o;
    }
  }

  // ---- memory-read term ----
  __syncthreads();
  {  // stage Mem^T hi [e][d] into sKh
    const int e2 = (tid & 31) * 2, d4 = (tid >> 5) * 4;
    const float* Memp = Mem + (long)shb * 4096;
    fv2 ld[4];
#pragma unroll
    for (int i = 0; i < 4; ++i) ld[i] = *(const fv2*)&Memp[(d4 + i) * 64 + e2];
#pragma unroll
    for (int je = 0; je < 2; ++je) {
      u16v4 hv;
#pragma unroll
      for (int i = 0; i < 4; ++i) hv[i] = f2h(ld[i][je]);
      *(u16v4*)&sKh[(e2 + je) * 72 + d4] = hv;
    }
  }
  if (tid < 64) {
    sZ[tid] = Zp[(long)shb * 64 + tid];
    sGate[tid] = 1.f / (1.f + __expf(-betas[h * 64 + tid]));
  }
  __syncthreads();

  // aq = elu(q)+1 split fp16; denom = aq . z (fp32)
  float dpart = 0.f;
#pragma unroll
  for (int dt = 0; dt < 2; ++dt) {
    u16v8 ah, al;
#pragma unroll
    for (int j = 0; j < 8; ++j) {
      const float x = (float)qh[dt][j] + (float)ql[dt][j];
      const float a = x > 0.f ? x + 1.f : __expf(x);
      dpart += a * sZ[dt * 32 + g * 8 + j];
      const unsigned short hb = f2h(a);
      ah[j] = hb;
      al[j] = f2h(a - h2f(hb));
    }
    qh[dt] = __builtin_bit_cast(hfv8, ah);
    ql[dt] = __builtin_bit_cast(hfv8, al);
  }
  dpart += __shfl_xor(dpart, 16);
  dpart += __shfl_xor(dpart, 32);
  const float invden = 1.f / (dpart + 1e-9f);
  const float invl = 1.f / l_run;

  const long obase = (long)qglob * D_DIM + h * 64;
#pragma unroll
  for (int et = 0; et < 4; ++et) {
    const int ro = (et * 16 + ln16) * 72 + g * 8;
    hfv8 mh0 = *(const hfv8*)&sKh[ro], mh1 = *(const hfv8*)&sKh[ro + 32];
    fv4 o = {};
    o = __builtin_amdgcn_mfma_f32_16x16x32_f16(mh0, qh[0], o, 0, 0, 0);
    o = __builtin_amdgcn_mfma_f32_16x16x32_f16(mh1, qh[1], o, 0, 0, 0);
    o = __builtin_amdgcn_mfma_f32_16x16x32_f16(mh0, ql[0], o, 0, 0, 0);
    o = __builtin_amdgcn_mfma_f32_16x16x32_f16(mh1, ql[1], o, 0, 0, 0);
    const fv4 gt = *(const fv4*)&sGate[et * 16 + g * 4];
    u32v4 st;
#pragma unroll
    for (int r = 0; r < 4; ++r) {
      const float att = gt[r] * o[r] * invden + (1.f - gt[r]) * O[et][r] * invl;
      st[r] = packh2(att);
    }
    *(u32v4*)&Op[obase + et * 16 + g * 4] = st;
  }
}

// ---------------- host launch ----------------
extern "C" void kernel_launch(void* const* d_in, const int* in_sizes, int n_in,
                              void* d_out, int out_size, void* d_ws, size_t ws_size,
                              hipStream_t stream) {
  (void)in_sizes; (void)n_in; (void)out_size;
  const float* x     = (const float*)d_in[0];
  const int*   mask  = (const int*)d_in[1];
  const float* wq    = (const float*)d_in[2];
  const float* wk    = (const float*)d_in[3];
  const float* wv    = (const float*)d_in[4];
  const float* wo    = (const float*)d_in[5];
  const float* wob   = (const float*)d_in[6];
  const float* betas = (const float*)d_in[7];
  float* out = (float*)d_out;

  const size_t TOK = (size_t)M_TOK * D_DIM;
  char* ws = (char*)d_ws;
  size_t off = 0;
  auto alloc = [&](size_t bytes) {
    char* p = ws + off;
    off += (bytes + 255) & ~(size_t)255;
    return p;
  };
  unsigned short* w16[4];
  for (int i = 0; i < 4; ++i)
    w16[i] = (unsigned short*)alloc((size_t)D_DIM * D_DIM * 2);  // 2 MiB each
  unsigned* qp = (unsigned*)alloc(TOK * 4);  // 128 MiB
  unsigned* kp = (unsigned*)alloc(TOK * 4);
  unsigned* vp = (unsigned*)alloc(TOK * 4);
  float* U   = (float*)alloc((size_t)B_DIM * NSEG * H_NUM * 4096 * 4);
  float* Mem = (float*)alloc((size_t)B_DIM * NSEG * H_NUM * 4096 * 4);
  float* Zs  = (float*)alloc((size_t)B_DIM * NSEG * H_NUM * 64 * 4);
  float* Zp  = (float*)alloc((size_t)B_DIM * NSEG * H_NUM * 64 * 4);
  // att output written IN-PLACE over qp.

  if (off > ws_size) return;

  const float* wsrc[4] = {wq, wk, wv, wo};
  for (int i = 0; i < 4; ++i)
    conv_w16<<<256, 256, 0, stream>>>(wsrc[i], w16[i], D_DIM * D_DIM / 4);

  const int ggrid = (D_DIM / 128) * (M_TOK / 128);  // 2048, XCD-swizzled
  gemm_bt<1><<<ggrid, 256, 0, stream>>>((const unsigned*)x, w16[0], nullptr, nullptr,
                                        qp, M_TOK, D_DIM, D_DIM);
  gemm_bt<1><<<ggrid, 256, 0, stream>>>((const unsigned*)x, w16[1], nullptr, nullptr,
                                        kp, M_TOK, D_DIM, D_DIM);
  gemm_bt<1><<<ggrid, 256, 0, stream>>>((const unsigned*)x, w16[2], nullptr, nullptr,
                                        vp, M_TOK, D_DIM, D_DIM);

  seg_outer_mfma<<<B_DIM * NSEG * H_NUM, 256, 0, stream>>>(kp, vp, U, Zs);
  seg_prefix<<<dim3(B_DIM * H_NUM, 8), 256, 0, stream>>>(U, Zs, Mem, Zp);

  for (int b = 0; b < B_DIM; ++b)
    attn_seg_mfma<<<NSEG * H_NUM * 4, 512, 0, stream>>>(qp, kp, vp, mask, Mem, Zp,
                                                        betas, qp, b);

  gemm_bt<0><<<ggrid, 256, 0, stream>>>(qp, w16[3], out, wob, nullptr,
                                        M_TOK, D_DIM, D_DIM);
}

// Round 13
// 709.247 us; speedup vs baseline: 2.1149x; 1.1972x over previous
//
#include <hip/hip_runtime.h>

typedef float fv2 __attribute__((ext_vector_type(2)));
typedef float fv4 __attribute__((ext_vector_type(4)));
typedef _Float16 hfv8 __attribute__((ext_vector_type(8)));
typedef unsigned short u16v4 __attribute__((ext_vector_type(4)));
typedef unsigned short u16v8 __attribute__((ext_vector_type(8)));
typedef unsigned int u32v4 __attribute__((ext_vector_type(4)));

#define B_DIM 4
#define L_DIM 8192
#define D_DIM 1024
#define H_NUM 16
#define NSEG 16
#define SEG_S 512
#define M_TOK (B_DIM * L_DIM)  // 32768

__device__ __forceinline__ unsigned short f2h(float f) {
  return __builtin_bit_cast(unsigned short, (_Float16)f);  // v_cvt_f16_f32 RNE
}
__device__ __forceinline__ float h2f(unsigned short u) {
  return (float)__builtin_bit_cast(_Float16, u);
}
// packed fp16 pair: hi in low 16 bits, lo residual in high 16 bits
__device__ __forceinline__ unsigned packh2(float v) {
  const _Float16 h = (_Float16)v;
  const unsigned short lb = __builtin_bit_cast(unsigned short, (_Float16)(v - (float)h));
  return (unsigned)__builtin_bit_cast(unsigned short, h) | ((unsigned)lb << 16);
}

// unpack 8 packed pairs (2 x u32v4) -> u16v8 hi plane and u16v8 lo plane
__device__ __forceinline__ void unpack8(u32v4 a, u32v4 b, u16v8& hi8, u16v8& lo8) {
  u32v4 hi, lo;
  hi[0] = __builtin_amdgcn_perm(a[1], a[0], 0x05040100u);
  hi[1] = __builtin_amdgcn_perm(a[3], a[2], 0x05040100u);
  hi[2] = __builtin_amdgcn_perm(b[1], b[0], 0x05040100u);
  hi[3] = __builtin_amdgcn_perm(b[3], b[2], 0x05040100u);
  lo[0] = __builtin_amdgcn_perm(a[1], a[0], 0x07060302u);
  lo[1] = __builtin_amdgcn_perm(a[3], a[2], 0x07060302u);
  lo[2] = __builtin_amdgcn_perm(b[1], b[0], 0x07060302u);
  lo[3] = __builtin_amdgcn_perm(b[3], b[2], 0x07060302u);
  hi8 = __builtin_bit_cast(u16v8, hi);
  lo8 = __builtin_bit_cast(u16v8, lo);
}
// hi plane only (4 perms) — used for K staging in attn
__device__ __forceinline__ u16v8 hi8of(u32v4 a, u32v4 b) {
  u32v4 hi;
  hi[0] = __builtin_amdgcn_perm(a[1], a[0], 0x05040100u);
  hi[1] = __builtin_amdgcn_perm(a[3], a[2], 0x05040100u);
  hi[2] = __builtin_amdgcn_perm(b[1], b[0], 0x05040100u);
  hi[3] = __builtin_amdgcn_perm(b[3], b[2], 0x05040100u);
  return __builtin_bit_cast(u16v8, hi);
}

// ---------------- fp32 -> single fp16 plane (weights and x) ----------------
__global__ __launch_bounds__(256) void conv_w16(
    const float* __restrict__ in, unsigned short* __restrict__ outp, int n4) {
  int i = blockIdx.x * 256 + threadIdx.x;
  const int stride = gridDim.x * 256;
  for (; i < n4; i += stride) {
    fv4 v = reinterpret_cast<const fv4*>(in)[i];
    u16v4 p;
#pragma unroll
    for (int j = 0; j < 4; ++j) p[j] = f2h(v[j]);
    reinterpret_cast<u16v4*>(outp)[i] = p;
  }
}

// ---------------- C[M,N] = A @ B^T, fp16 MFMA, global_load_lds 2-phase ----------------
// A,B: plain fp16 row-major [.,K]. LDS linear, bank-swizzle via inverse-swizzled
// global source + swizzled ds_read (rule #21): chunk ^= (row>>1)&3 (involution).
// OMODE: 0 = fp32 + bias, 1 = packed fp16-pair u32, 2 = single fp16.
template <int OMODE>
__global__ __launch_bounds__(256, 4) void gemm_bt(
    const _Float16* __restrict__ A16, const _Float16* __restrict__ B16,
    float* __restrict__ C, const float* __restrict__ bias,
    unsigned* __restrict__ Cp, unsigned short* __restrict__ Cs,
    int M, int N, int K) {
  __shared__ _Float16 sA[2][4096];  // [buf][128 rows x 32 k]
  __shared__ _Float16 sB[2][4096];
  const int tid = threadIdx.x;
  const int lane = tid & 63;
  const int wv = tid >> 6;
  const int wr = wv >> 1, wc = wv & 1;
  const int g = lane >> 4, ln16 = lane & 15;

  // T1 XCD swizzle: 8 N-tiles of one M-panel share one XCD.
  const int hw = blockIdx.x;
  const int xcd = hw & 7;
  const int rem = hw >> 3;
  const int ntile = rem & 7;
  const int yhi = rem >> 3;
  const int mtile = yhi * 8 + xcd;
  const int mBase = mtile * 128;
  const int nBase = ntile * 128;

  fv4 acc[4][4] = {};

  // staging: wave wv covers rows [wv*32, wv*32+32); issue i covers 16 rows.
  // lane l -> row = wv*32 + i*16 + (l>>2), LDS chunk c_lds = l&3,
  // global chunk cg = c_lds ^ sw(row); sw(row) = (row>>1)&3 = (l>>3)&3 here.
  const int srow = lane >> 2;
  const int cgx = ((lane & 3) ^ ((lane >> 3) & 3)) * 8;  // fp16 units
  const long aStageBase = (long)(mBase + wv * 32 + srow) * K + cgx;
  const long bStageBase = (long)(nBase + wv * 32 + srow) * K + cgx;
  // frag reads: row arow0+i*16, chunk g -> LDS chunk g ^ ((ln16>>1)&3)
  const int rgx = (g ^ ((ln16 >> 1) & 3)) * 8;
  const int arow0 = wr * 64 + ln16;
  const int brow0 = wc * 64 + ln16;

  auto STAGE = [&](int t, int bi) {
#pragma unroll
    for (int i = 0; i < 2; ++i) {
      __builtin_amdgcn_global_load_lds(
          (const __attribute__((address_space(1))) void*)(A16 + aStageBase + (long)i * 16 * K + t * 32),
          (__attribute__((address_space(3))) void*)&sA[bi][wv * 1024 + i * 512], 16, 0, 0);
      __builtin_amdgcn_global_load_lds(
          (const __attribute__((address_space(1))) void*)(B16 + bStageBase + (long)i * 16 * K + t * 32),
          (__attribute__((address_space(3))) void*)&sB[bi][wv * 1024 + i * 512], 16, 0, 0);
    }
  };
  auto COMPUTE = [&](int bi) {
    hfv8 fa[4], fb[4];
#pragma unroll
    for (int i = 0; i < 4; ++i) {
      fa[i] = *(const hfv8*)&sA[bi][(arow0 + i * 16) * 32 + rgx];
      fb[i] = *(const hfv8*)&sB[bi][(brow0 + i * 16) * 32 + rgx];
    }
#pragma unroll
    for (int i = 0; i < 4; ++i)
#pragma unroll
      for (int j = 0; j < 4; ++j)
        acc[i][j] = __builtin_amdgcn_mfma_f32_16x16x32_f16(fa[i], fb[j], acc[i][j], 0, 0, 0);
  };

  const int NT = K / 32;  // 32
  STAGE(0, 0);
  asm volatile("s_waitcnt vmcnt(0)" ::: "memory");
  __builtin_amdgcn_s_barrier();
  for (int t = 0; t < NT; t += 2) {
    STAGE(t + 1, 1);          // into buf1 (last read at t-1, barrier-protected)
    COMPUTE(0);               // loads of t+1 fly under ds_read+MFMA
    asm volatile("s_waitcnt vmcnt(0) lgkmcnt(0)" ::: "memory");
    __builtin_amdgcn_s_barrier();
    if (t + 2 < NT) STAGE(t + 2, 0);
    COMPUTE(1);
    asm volatile("s_waitcnt vmcnt(0) lgkmcnt(0)" ::: "memory");
    __builtin_amdgcn_s_barrier();
  }

  // C/D layout (m89, dtype-independent): col = lane&15, row = 4*(lane>>4) + reg
  const int crow0 = mBase + wr * 64 + ((lane >> 4) << 2);
  const int ccol0 = nBase + wc * 64 + (lane & 15);
#pragma unroll
  for (int j = 0; j < 4; ++j) {
    const int col = ccol0 + j * 16;
    float bv = 0.f;
    if (OMODE == 0) bv = bias ? bias[col] : 0.f;
#pragma unroll
    for (int i = 0; i < 4; ++i) {
      const long rb = (long)(crow0 + i * 16) * N + col;
#pragma unroll
      for (int r = 0; r < 4; ++r) {
        if (OMODE == 0) C[rb + (long)r * N] = acc[i][j][r] + bv;
        else if (OMODE == 1) Cp[rb + (long)r * N] = packh2(acc[i][j][r]);
        else Cs[rb + (long)r * N] = f2h(acc[i][j][r]);
      }
    }
  }
}

// ---------------- per-(b,seg,h) outer products: U = akT.v, fp16 2-product ----------------
__global__ __launch_bounds__(256) void seg_outer_mfma(
    const unsigned* __restrict__ Kp, const unsigned short* __restrict__ V16,
    float* __restrict__ U, float* __restrict__ Zs) {
  __shared__ _Float16 sAh[64 * 64], sAl[64 * 64];  // akT [d][s]
  __shared__ _Float16 sVh[64 * 64];                // vT  [e][s]
  __shared__ float sZf[64];
  const int bid = blockIdx.x;  // b*256 + seg*16 + h
  const int b = bid >> 8, seg = (bid >> 4) & 15, h = bid & 15;
  const int tid = threadIdx.x;
  const int lane = tid & 63, w = tid >> 6;
  const int g = lane >> 4, ln16 = lane & 15;
  const long base = ((long)b * L_DIM + (long)seg * SEG_S) * D_DIM + h * 64;

  if (tid < 64) sZf[tid] = 0.f;
  fv4 acc[4] = {};
  float zacc = 0.f;
  const int strow = tid & 63;
  const int sg0 = (tid >> 6) * 16;
  const int wsw = (strow & 7) << 3;
  const int rsw = (ln16 & 7) << 3;

  for (int c = 0; c < 8; ++c) {
    __syncthreads();
#pragma unroll
    for (int jj = 0; jj < 2; ++jj) {
      u16v8 ah, al, vh;
#pragma unroll
      for (int i = 0; i < 8; ++i) {
        const long gidx = base + (long)(c * 64 + sg0 + jj * 8 + i) * D_DIM + strow;
        const unsigned ku = Kp[gidx];
        const float kv = h2f((unsigned short)(ku & 0xffffu)) +
                         h2f((unsigned short)(ku >> 16));
        const float a = kv > 0.f ? kv + 1.f : __expf(kv);
        zacc += a;
        const unsigned short hb = f2h(a);
        ah[i] = hb;
        al[i] = f2h(a - h2f(hb));
        vh[i] = V16[gidx];
      }
      const int col = (sg0 + jj * 8) ^ wsw;
      *(u16v8*)&sAh[strow * 64 + col] = ah;
      *(u16v8*)&sAl[strow * 64 + col] = al;
      *(u16v8*)&sVh[strow * 64 + col] = vh;
    }
    __syncthreads();
#pragma unroll
    for (int kf = 0; kf < 2; ++kf) {
      const int so = (kf * 32 + g * 8) ^ rsw;
      hfv8 aH = *(const hfv8*)&sAh[(w * 16 + ln16) * 64 + so];
      hfv8 aL = *(const hfv8*)&sAl[(w * 16 + ln16) * 64 + so];
#pragma unroll
      for (int et = 0; et < 4; ++et) {
        hfv8 bH = *(const hfv8*)&sVh[(et * 16 + ln16) * 64 + so];
        acc[et] = __builtin_amdgcn_mfma_f32_16x16x32_f16(aH, bH, acc[et], 0, 0, 0);
        acc[et] = __builtin_amdgcn_mfma_f32_16x16x32_f16(aL, bH, acc[et], 0, 0, 0);
      }
    }
  }
  atomicAdd(&sZf[strow], zacc);
  __syncthreads();

  const long ub = (long)bid * 4096;
#pragma unroll
  for (int et = 0; et < 4; ++et)
#pragma unroll
    for (int r = 0; r < 4; ++r)
      U[ub + (long)(w * 16 + g * 4 + r) * 64 + et * 16 + ln16] = acc[et][r];
  if (tid < 64) Zs[(long)bid * 64 + tid] = sZf[tid];
}

// ---------------- exclusive prefix over segments (per b,h) ----------------
__global__ __launch_bounds__(256) void seg_prefix(
    const float* __restrict__ U, const float* __restrict__ Zs,
    float* __restrict__ Mem, float* __restrict__ Zp) {
  const int bh = blockIdx.x;
  const int b = bh >> 4, h = bh & 15;
  const int jc = blockIdx.y;
  const int tid = threadIdx.x;
  for (int j = jc * 512 + tid; j < jc * 512 + 512; j += 256) {
    float run = 0.f;
#pragma unroll
    for (int t = 0; t < NSEG; ++t) {
      const long idx = ((long)(b * 256 + t * 16 + h)) * 4096 + j;
      Mem[idx] = run;
      run += U[idx];
    }
  }
  if (jc == 0 && tid < 64) {
    float run = 0.f;
#pragma unroll
    for (int t = 0; t < NSEG; ++t) {
      const long idx = ((long)(b * 256 + t * 16 + h)) * 64 + tid;
      Zp[idx] = run;
      run += Zs[idx];
    }
  }
}

// ---------------- MFMA segment attention, fp16; out = single fp16 ----------------
__global__ __launch_bounds__(512, 4) void attn_seg_mfma(
    const unsigned* __restrict__ Qp, const unsigned* __restrict__ Kp,
    const unsigned short* __restrict__ V16, const int* __restrict__ mask,
    const float* __restrict__ Mem, const float* __restrict__ Zp,
    const float* __restrict__ betas, unsigned short* __restrict__ Op16, int b) {
  __shared__ _Float16 sKh[64 * 72];   // K chunk [key][d] hi; later Mem^T [e][d] hi
  __shared__ _Float16 sVTh[64 * 64];  // V^T [e][key], swizzled
  __shared__ _Float16 sP[8][16 * 72]; // per-wave P fp16 [q][key]
  __shared__ float sMadd[64], sZ[64], sGate[64];

  const int bx = (blockIdx.x & 7) * 128 + (blockIdx.x >> 3);  // T1 bijective
  const int qblk = bx & 3, h = (bx >> 2) & 15, seg = bx >> 6;
  const int shb = b * 256 + seg * 16 + h;
  const int tid = threadIdx.x;
  const int lane = tid & 63, w = tid >> 6;
  const int g = lane >> 4, ln16 = lane & 15;
  const int rsw = (ln16 & 7) << 3;

  const int qglob = b * L_DIM + seg * SEG_S + qblk * 128 + w * 16 + ln16;
  const long qbase = (long)qglob * D_DIM + h * 64;
  hfv8 qh[2], ql[2];
#pragma unroll
  for (int dt = 0; dt < 2; ++dt) {
    u32v4 a = *(const u32v4*)&Qp[qbase + dt * 32 + g * 8];
    u32v4 bb = *(const u32v4*)&Qp[qbase + dt * 32 + g * 8 + 4];
    u16v8 hi8, lo8;
    unpack8(a, bb, hi8, lo8);
    qh[dt] = __builtin_bit_cast(hfv8, hi8);
    ql[dt] = __builtin_bit_cast(hfv8, lo8);
  }

  fv4 O[4] = {};
  float m_run = -1e30f, l_run = 0.f;
  const long kvbase0 = ((long)b * L_DIM + (long)seg * SEG_S) * D_DIM + h * 64;

  for (int c = 0; c < 8; ++c) {
    __syncthreads();
    {  // stage K hi [64 key][64 d]
      const int row = tid >> 3, d0 = (tid & 7) * 8;
      const long ga = kvbase0 + (long)(c * 64 + row) * D_DIM + d0;
      u32v4 a = *(const u32v4*)&Kp[ga], bb = *(const u32v4*)&Kp[ga + 4];
      *(u16v8*)&sKh[row * 72 + d0] = hi8of(a, bb);
    }
    {  // stage V^T [64 e][64 key], XOR-swizzled
      const int e = tid & 63, kg = (tid >> 6) * 8;
      u16v8 hv;
#pragma unroll
      for (int j = 0; j < 8; ++j)
        hv[j] = V16[kvbase0 + (long)(c * 64 + kg + j) * D_DIM + e];
      *(u16v8*)&sVTh[e * 64 + (kg ^ ((e & 7) << 3))] = hv;
    }
    if (tid < 64)
      sMadd[tid] = (mask[b * L_DIM + seg * SEG_S + c * 64 + tid] == 0) ? -1e9f : 0.f;
    __syncthreads();

    fv4 madd[4];
#pragma unroll
    for (int kt = 0; kt < 4; ++kt) madd[kt] = *(const fv4*)&sMadd[kt * 16 + g * 4];

    // S^T = K_hi . (Q_hi + Q_lo)
    fv4 sc[4];
#pragma unroll
    for (int kt = 0; kt < 4; ++kt) {
      const int ro = (kt * 16 + ln16) * 72 + g * 8;
      hfv8 kh0 = *(const hfv8*)&sKh[ro], kh1 = *(const hfv8*)&sKh[ro + 32];
      fv4 s = {};
      s = __builtin_amdgcn_mfma_f32_16x16x32_f16(kh0, qh[0], s, 0, 0, 0);
      s = __builtin_amdgcn_mfma_f32_16x16x32_f16(kh1, qh[1], s, 0, 0, 0);
      s = __builtin_amdgcn_mfma_f32_16x16x32_f16(kh0, ql[0], s, 0, 0, 0);
      s = __builtin_amdgcn_mfma_f32_16x16x32_f16(kh1, ql[1], s, 0, 0, 0);
      sc[kt] = s;
    }
    // online softmax (defer-max THR=8)
    float pmax = -3.0e38f;
#pragma unroll
    for (int kt = 0; kt < 4; ++kt)
#pragma unroll
      for (int r = 0; r < 4; ++r) {
        const float v = __builtin_fmaf(sc[kt][r], 0.125f, madd[kt][r]);
        sc[kt][r] = v;
        pmax = fmaxf(pmax, v);
      }
    pmax = fmaxf(pmax, __shfl_xor(pmax, 16));
    pmax = fmaxf(pmax, __shfl_xor(pmax, 32));
    if (pmax > m_run + 8.f) {
      const float resc = __expf(m_run - pmax);
      l_run *= resc;
#pragma unroll
      for (int et = 0; et < 4; ++et)
#pragma unroll
        for (int r = 0; r < 4; ++r) O[et][r] *= resc;
      m_run = pmax;
    }
    float psum = 0.f;
#pragma unroll
    for (int kt = 0; kt < 4; ++kt) {
      u16v4 pv;
#pragma unroll
      for (int r = 0; r < 4; ++r) {
        const unsigned short hb = f2h(__expf(sc[kt][r] - m_run));
        pv[r] = hb;
        psum += h2f(hb);
      }
      *(u16v4*)&sP[w][ln16 * 72 + kt * 16 + g * 4] = pv;
    }
    psum += __shfl_xor(psum, 16);
    psum += __shfl_xor(psum, 32);
    l_run += psum;

    hfv8 pf0 = *(const hfv8*)&sP[w][ln16 * 72 + g * 8];
    hfv8 pf1 = *(const hfv8*)&sP[w][ln16 * 72 + 32 + g * 8];
    // O^T += V^T . P
#pragma unroll
    for (int et = 0; et < 4; ++et) {
      const int rb = (et * 16 + ln16) * 64;
      hfv8 vh0 = *(const hfv8*)&sVTh[rb + ((g * 8) ^ rsw)];
      hfv8 vh1 = *(const hfv8*)&sVTh[rb + ((g * 8 + 32) ^ rsw)];
      fv4 o = O[et];
      o = __builtin_amdgcn_mfma_f32_16x16x32_f16(vh0, pf0, o, 0, 0, 0);
      o = __builtin_amdgcn_mfma_f32_16x16x32_f16(vh1, pf1, o, 0, 0, 0);
      O[et] = o;
    }
  }

  // ---- memory-read term ----
  __syncthreads();
  {  // stage Mem^T hi [e][d] into sKh
    const int e2 = (tid & 31) * 2, d4 = (tid >> 5) * 4;
    const float* Memp = Mem + (long)shb * 4096;
    fv2 ld[4];
#pragma unroll
    for (int i = 0; i < 4; ++i) ld[i] = *(const fv2*)&Memp[(d4 + i) * 64 + e2];
#pragma unroll
    for (int je = 0; je < 2; ++je) {
      u16v4 hv;
#pragma unroll
      for (int i = 0; i < 4; ++i) hv[i] = f2h(ld[i][je]);
      *(u16v4*)&sKh[(e2 + je) * 72 + d4] = hv;
    }
  }
  if (tid < 64) {
    sZ[tid] = Zp[(long)shb * 64 + tid];
    sGate[tid] = 1.f / (1.f + __expf(-betas[h * 64 + tid]));
  }
  __syncthreads();

  // aq = elu(q)+1 split fp16; denom = aq . z (fp32)
  float dpart = 0.f;
#pragma unroll
  for (int dt = 0; dt < 2; ++dt) {
    u16v8 ah, al;
#pragma unroll
    for (int j = 0; j < 8; ++j) {
      const float x = (float)qh[dt][j] + (float)ql[dt][j];
      const float a = x > 0.f ? x + 1.f : __expf(x);
      dpart += a * sZ[dt * 32 + g * 8 + j];
      const unsigned short hb = f2h(a);
      ah[j] = hb;
      al[j] = f2h(a - h2f(hb));
    }
    qh[dt] = __builtin_bit_cast(hfv8, ah);
    ql[dt] = __builtin_bit_cast(hfv8, al);
  }
  dpart += __shfl_xor(dpart, 16);
  dpart += __shfl_xor(dpart, 32);
  const float invden = 1.f / (dpart + 1e-9f);
  const float invl = 1.f / l_run;

  const long obase = (long)qglob * D_DIM + h * 64;
#pragma unroll
  for (int et = 0; et < 4; ++et) {
    const int ro = (et * 16 + ln16) * 72 + g * 8;
    hfv8 mh0 = *(const hfv8*)&sKh[ro], mh1 = *(const hfv8*)&sKh[ro + 32];
    fv4 o = {};
    o = __builtin_amdgcn_mfma_f32_16x16x32_f16(mh0, qh[0], o, 0, 0, 0);
    o = __builtin_amdgcn_mfma_f32_16x16x32_f16(mh1, qh[1], o, 0, 0, 0);
    o = __builtin_amdgcn_mfma_f32_16x16x32_f16(mh0, ql[0], o, 0, 0, 0);
    o = __builtin_amdgcn_mfma_f32_16x16x32_f16(mh1, ql[1], o, 0, 0, 0);
    const fv4 gt = *(const fv4*)&sGate[et * 16 + g * 4];
    u16v4 st;
#pragma unroll
    for (int r = 0; r < 4; ++r) {
      const float att = gt[r] * o[r] * invden + (1.f - gt[r]) * O[et][r] * invl;
      st[r] = f2h(att);
    }
    *(u16v4*)&Op16[obase + et * 16 + g * 4] = st;
  }
}

// ---------------- host launch ----------------
extern "C" void kernel_launch(void* const* d_in, const int* in_sizes, int n_in,
                              void* d_out, int out_size, void* d_ws, size_t ws_size,
                              hipStream_t stream) {
  (void)in_sizes; (void)n_in; (void)out_size;
  const float* x     = (const float*)d_in[0];
  const int*   mask  = (const int*)d_in[1];
  const float* wq    = (const float*)d_in[2];
  const float* wk    = (const float*)d_in[3];
  const float* wv    = (const float*)d_in[4];
  const float* wo    = (const float*)d_in[5];
  const float* wob   = (const float*)d_in[6];
  const float* betas = (const float*)d_in[7];
  float* out = (float*)d_out;

  const size_t TOK = (size_t)M_TOK * D_DIM;  // 33.5M elements
  char* ws = (char*)d_ws;
  size_t off = 0;
  auto alloc = [&](size_t bytes) {
    char* p = ws + off;
    off += (bytes + 255) & ~(size_t)255;
    return p;
  };
  unsigned short* w16[4];
  for (int i = 0; i < 4; ++i)
    w16[i] = (unsigned short*)alloc((size_t)D_DIM * D_DIM * 2);  // 2 MiB each
  unsigned short* x16 = (unsigned short*)alloc(TOK * 2);  // 64 MiB
  unsigned* qp = (unsigned*)alloc(TOK * 4);               // 128 MiB (pairs)
  unsigned* kp = (unsigned*)alloc(TOK * 4);               // 128 MiB (pairs)
  unsigned short* vp16 = (unsigned short*)alloc(TOK * 2); // 64 MiB
  float* U   = (float*)alloc((size_t)B_DIM * NSEG * H_NUM * 4096 * 4);
  float* Mem = (float*)alloc((size_t)B_DIM * NSEG * H_NUM * 4096 * 4);
  float* Zs  = (float*)alloc((size_t)B_DIM * NSEG * H_NUM * 64 * 4);
  float* Zp  = (float*)alloc((size_t)B_DIM * NSEG * H_NUM * 64 * 4);
  unsigned short* att16 = x16;  // x16 dead after QKV GEMMs — reuse (64 MiB)

  if (off > ws_size) return;

  const float* wsrc[4] = {wq, wk, wv, wo};
  for (int i = 0; i < 4; ++i)
    conv_w16<<<256, 256, 0, stream>>>(wsrc[i], w16[i], D_DIM * D_DIM / 4);
  conv_w16<<<2048, 256, 0, stream>>>(x, x16, (int)(TOK / 4));

  const int ggrid = (D_DIM / 128) * (M_TOK / 128);  // 2048, XCD-swizzled
  gemm_bt<1><<<ggrid, 256, 0, stream>>>(
      (const _Float16*)x16, (const _Float16*)w16[0], nullptr, nullptr, qp, nullptr,
      M_TOK, D_DIM, D_DIM);
  gemm_bt<1><<<ggrid, 256, 0, stream>>>(
      (const _Float16*)x16, (const _Float16*)w16[1], nullptr, nullptr, kp, nullptr,
      M_TOK, D_DIM, D_DIM);
  gemm_bt<2><<<ggrid, 256, 0, stream>>>(
      (const _Float16*)x16, (const _Float16*)w16[2], nullptr, nullptr, nullptr, vp16,
      M_TOK, D_DIM, D_DIM);

  seg_outer_mfma<<<B_DIM * NSEG * H_NUM, 256, 0, stream>>>(kp, vp16, U, Zs);
  seg_prefix<<<dim3(B_DIM * H_NUM, 8), 256, 0, stream>>>(U, Zs, Mem, Zp);

  for (int b = 0; b < B_DIM; ++b)
    attn_seg_mfma<<<NSEG * H_NUM * 4, 512, 0, stream>>>(qp, kp, vp16, mask, Mem, Zp,
                                                        betas, att16, b);

  gemm_bt<0><<<ggrid, 256, 0, stream>>>(
      (const _Float16*)att16, (const _Float16*)w16[3], out, wob, nullptr, nullptr,
      M_TOK, D_DIM, D_DIM);
}